// Round 2
// baseline (693.604 us; speedup 1.0000x reference)
//
#include <hip/hip_runtime.h>
#include <hip/hip_bf16.h>
#include <stdint.h>

typedef __hip_bfloat16 bf16;
typedef __attribute__((ext_vector_type(8))) short short8;
typedef __attribute__((ext_vector_type(4))) float f32x4;

#define SCALE_ 0.08838834764831845f  // 1/sqrt(128)

static __device__ __forceinline__ float bf2f(short u) {
  unsigned int x = ((unsigned int)(unsigned short)u) << 16;
  return __builtin_bit_cast(float, x);
}
static __device__ __forceinline__ short f2bf(float f) {
  __hip_bfloat16 h = __float2bfloat16(f);
  return __builtin_bit_cast(short, h);
}
static __device__ __forceinline__ f32x4 mfma16(short8 a, short8 b, f32x4 c) {
  return __builtin_amdgcn_mfma_f32_16x16x32_bf16(a, b, c, 0, 0, 0);
}
static __device__ __forceinline__ void gl_lds16(const bf16* g, bf16* l) {
  __builtin_amdgcn_global_load_lds(
      (const __attribute__((address_space(1))) unsigned int*)g,
      (__attribute__((address_space(3))) unsigned int*)l, 16, 0, 0);
}

// ---------------------------------------------------------------------------
// f32 -> bf16 conversion for x, wq, wk, wv, wo, prompt (one fused launch).
// 2048 elems per block (256 thr x 8). Segment picked by blockIdx.x range.
// ---------------------------------------------------------------------------
__global__ __launch_bounds__(256) void cvt6(
    const float* __restrict__ sx, const float* __restrict__ sq,
    const float* __restrict__ sk, const float* __restrict__ sv,
    const float* __restrict__ so, const float* __restrict__ sp,
    bf16* __restrict__ dx, bf16* __restrict__ dq, bf16* __restrict__ dk,
    bf16* __restrict__ dv, bf16* __restrict__ d4, bf16* __restrict__ dp)
{
  int b = blockIdx.x;
  const float* s; bf16* d; int off;
  if (b < 4096)       { s = sx; d = dx; off = b; }
  else if (b < 12288) { s = sq; d = dq; off = b - 4096; }
  else if (b < 20480) { s = sk; d = dk; off = b - 12288; }
  else if (b < 28672) { s = sv; d = dv; off = b - 20480; }
  else if (b < 36864) { s = so; d = d4; off = b - 28672; }
  else                { s = sp; d = dp; off = b - 36864; }
  long base = (long)off * 2048 + threadIdx.x * 8;
  f32x4 a = *(const f32x4*)(s + base);
  f32x4 c = *(const f32x4*)(s + base + 4);
  short8 o;
#pragma unroll
  for (int j = 0; j < 4; j++) { o[j] = f2bf(a[j]); o[4 + j] = f2bf(c[j]); }
  *(short8*)(d + base) = o;
}

// ---------------------------------------------------------------------------
// GEMM: C[m][n] = sum_k A[m][k] * Bw[n][k]   (A row-major MxK, Bw row-major NxK)
// K = N = 4096 fixed. 128x128 tile, BK=32, 4 waves (2x2), 4x4 16x16x32 frags.
// Rows >= M1 come from A2 (prompt rows, clamped); their outputs go to Cp.
// grid.z selects (Bw, C, Cp) triple for the fused QKV launch.
// If CF != null, output is written as f32 to CF instead (rows all < M1).
// ---------------------------------------------------------------------------
__global__ __launch_bounds__(256) void gemm_bt(
    const bf16* __restrict__ A, const bf16* __restrict__ A2,
    const bf16* __restrict__ B0, const bf16* __restrict__ B1, const bf16* __restrict__ B2w,
    bf16* __restrict__ C0, bf16* __restrict__ C1, bf16* __restrict__ C2,
    bf16* __restrict__ P1, bf16* __restrict__ P2,
    float* __restrict__ CF,
    int M1, int Mtot)
{
  const int K = 4096, N = 4096;
  __shared__ bf16 As[128 * 32];
  __shared__ bf16 Bs[128 * 32];
  const int tid = threadIdx.x;
  const int w = tid >> 6, l = tid & 63;
  const int lr = l & 15, lg = l >> 4;
  const int z = blockIdx.z;
  const bf16* Bw = (z == 0) ? B0 : ((z == 1) ? B1 : B2w);
  bf16* C  = (z == 0) ? C0 : ((z == 1) ? C1 : C2);
  bf16* Cp = (z == 0) ? (bf16*)0 : ((z == 1) ? P1 : P2);
  const long m0 = (long)blockIdx.x * 128;
  const long n0 = (long)blockIdx.y * 128;
  const int cb1 = w * 64, cb2 = 256 + w * 64;
  const int i1 = cb1 + l, i2 = cb2 + l;

  // staging source pointers (chunk i -> row i>>2, 8-elem col chunk i&3)
  const bf16* aA;
  const bf16* aB;
  {
    long r1 = m0 + (i1 >> 2);
    long r2 = m0 + (i2 >> 2);
    const bf16* p1;
    const bf16* p2;
    if (r1 < M1) p1 = A + r1 * K;
    else { long rr = r1 - M1; long mx = (long)(Mtot - M1) - 1; if (rr > mx) rr = mx; p1 = A2 + rr * K; }
    if (r2 < M1) p2 = A + r2 * K;
    else { long rr = r2 - M1; long mx = (long)(Mtot - M1) - 1; if (rr > mx) rr = mx; p2 = A2 + rr * K; }
    aA = p1 + (i1 & 3) * 8;
    aB = p2 + (i2 & 3) * 8;
  }
  const bf16* bA = Bw + (n0 + (i1 >> 2)) * K + (i1 & 3) * 8;
  const bf16* bB = Bw + (n0 + (i2 >> 2)) * K + (i2 & 3) * 8;

  const int wm = (w >> 1) * 64, wn = (w & 1) * 64;
  f32x4 acc[4][4];
#pragma unroll
  for (int i = 0; i < 4; i++)
#pragma unroll
    for (int j = 0; j < 4; j++) acc[i][j] = (f32x4){0.f, 0.f, 0.f, 0.f};

  for (int t = 0; t < K / 32; ++t) {
    gl_lds16(aA, As + cb1 * 8);
    gl_lds16(aB, As + cb2 * 8);
    gl_lds16(bA, Bs + cb1 * 8);
    gl_lds16(bB, Bs + cb2 * 8);
    aA += 32; aB += 32; bA += 32; bB += 32;
    __syncthreads();  // drains vmcnt: staged tile visible
    short8 af[4], bfr[4];
#pragma unroll
    for (int mi = 0; mi < 4; mi++)
      af[mi] = *(const short8*)(As + (wm + mi * 16 + lr) * 32 + lg * 8);
#pragma unroll
    for (int ni = 0; ni < 4; ni++)
      bfr[ni] = *(const short8*)(Bs + (wn + ni * 16 + lr) * 32 + lg * 8);
#pragma unroll
    for (int mi = 0; mi < 4; mi++)
#pragma unroll
      for (int ni = 0; ni < 4; ni++)
        acc[mi][ni] = mfma16(af[mi], bfr[ni], acc[mi][ni]);
    __syncthreads();  // protect LDS before next stage
  }

  // epilogue: C/D layout col=lane&15, row=(lane>>4)*4+r
#pragma unroll
  for (int mi = 0; mi < 4; mi++) {
#pragma unroll
    for (int ni = 0; ni < 4; ni++) {
      long col = n0 + wn + ni * 16 + lr;
      f32x4 v = acc[mi][ni];
#pragma unroll
      for (int r = 0; r < 4; r++) {
        long row = m0 + wm + mi * 16 + lg * 4 + r;
        if (CF) {
          CF[row * N + col] = v[r];
        } else if (row < M1) {
          *(short*)(C + row * N + col) = f2bf(v[r]);
        } else if (Cp != 0 && row < Mtot) {
          *(short*)(Cp + (row - M1) * N + col) = f2bf(v[r]);
        }
      }
    }
  }
}

// ---------------------------------------------------------------------------
// RoPE in-place on q / k  ([2048][4096], col = h*128 + d, pairs interleaved)
// grid (2048 rows, 2 tensors), 256 threads, 16 bf16 per thread; freqs f32.
// ---------------------------------------------------------------------------
__global__ __launch_bounds__(256) void rope_qk(
    bf16* __restrict__ Q, bf16* __restrict__ Kb,
    const float* __restrict__ FC, const float* __restrict__ FS)
{
  const int row = blockIdx.x;
  const int s = row & 1023;
  const int t = threadIdx.x;
  bf16* base = (blockIdx.y ? Kb : Q) + (long)row * 4096 + t * 16;
  short8 v0 = *(const short8*)base;
  short8 v1 = *(const short8*)(base + 8);
  const float* cp = FC + s * 64 + (t & 7) * 8;
  const float* sp = FS + s * 64 + (t & 7) * 8;
  f32x4 c0 = *(const f32x4*)cp;
  f32x4 c1 = *(const f32x4*)(cp + 4);
  f32x4 s0 = *(const f32x4*)sp;
  f32x4 s1 = *(const f32x4*)(sp + 4);
  short8 o0, o1;
#pragma unroll
  for (int j = 0; j < 4; j++) {
    float c = c0[j], sn = s0[j];
    float e = bf2f(v0[2 * j]), od = bf2f(v0[2 * j + 1]);
    o0[2 * j] = f2bf(e * c - od * sn);
    o0[2 * j + 1] = f2bf(e * sn + od * c);
    float c2 = c1[j], sn2 = s1[j];
    float e2 = bf2f(v1[2 * j]), od2 = bf2f(v1[2 * j + 1]);
    o1[2 * j] = f2bf(e2 * c2 - od2 * sn2);
    o1[2 * j + 1] = f2bf(e2 * sn2 + od2 * c2);
  }
  *(short8*)base = o0;
  *(short8*)(base + 8) = o1;
}

// ---------------------------------------------------------------------------
// V transpose: v[b][s][h][d] -> vT[bh][d][s]   (so PV B-frags are contiguous)
// grid (16 s-tiles of 64, 64 bh), 256 threads, LDS swizzled [64][128]
// ---------------------------------------------------------------------------
__global__ __launch_bounds__(256) void transpose_v(
    const bf16* __restrict__ V, bf16* __restrict__ VT)
{
  __shared__ bf16 T[64 * 128];
  const int tid = threadIdx.x;
  const int st = blockIdx.x * 64, bh = blockIdx.y;
  const int b = bh >> 5, h = bh & 31;
  const bf16* src = V + ((long)(b * 1024 + st)) * 4096 + h * 128;
#pragma unroll
  for (int rr = 0; rr < 4; ++rr) {
    int i = tid + rr * 256;          // 1024 chunks of 16B: s_l = i>>4, c = i&15
    int s_l = i >> 4, c = i & 15;
    short8 v = *(const short8*)(src + (long)s_l * 4096 + c * 8);
    *(short8*)((char*)T + s_l * 256 + ((c ^ (s_l & 7)) * 16)) = v;
  }
  __syncthreads();
#pragma unroll
  for (int rr = 0; rr < 4; ++rr) {
    int i = tid + rr * 256;          // 1024 out-chunks: d = i>>3, cs = i&7
    int d = i >> 3, cs = i & 7;
    short8 ov;
#pragma unroll
    for (int e = 0; e < 8; e++) {
      int s_l = cs * 8 + e;
      ov[e] = *(const short*)((char*)T + s_l * 256 + (((d >> 3) ^ (s_l & 7)) * 16) + (d & 7) * 2);
    }
    *(short8*)(VT + ((long)bh * 128 + d) * 1024 + st + cs * 8) = ov;
  }
}

// ---------------------------------------------------------------------------
// Flash attention, causal, + fused gated prompt attention.
// grid (16 q-blocks of 64, 64 bh), 4 waves x 16 q-rows each, KV tile = 32.
// K tile LDS [32][128] w/ XOR swizzle (pre-applied on global src);
// V read from pre-transposed VT, LDS [128][32] w/ 2-bit XOR swizzle.
// ---------------------------------------------------------------------------
__global__ __launch_bounds__(256) void flash_attn(
    const bf16* __restrict__ Q, const bf16* __restrict__ Kg, const bf16* __restrict__ VT,
    const bf16* __restrict__ PK, const bf16* __restrict__ PV,
    const float* __restrict__ GATE, bf16* __restrict__ O)
{
  __shared__ bf16 Kl[32 * 128];
  __shared__ bf16 Vl[128 * 32];
  __shared__ bf16 PKl[16 * 128];
  __shared__ bf16 PVl[128 * 16];
  __shared__ bf16 Pl[4][16 * 32];
  const int tid = threadIdx.x, w = tid >> 6, l = tid & 63;
  const int lg = l >> 4, lr = l & 15;
  const int qb = blockIdx.x, bh = blockIdx.y;
  const int b = bh >> 5, h = bh & 31;
  const int q0 = qb * 64 + w * 16;

  // Q fragments (16 rows x 128, 4 k-chunks)
  short8 qf[4];
  {
    const bf16* qp = Q + ((long)(b * 1024 + q0 + lr)) * 4096 + h * 128 + lg * 8;
#pragma unroll
    for (int c = 0; c < 4; c++) qf[c] = *(const short8*)(qp + c * 32);
  }
  // stage prompt-K like a K tile (rows 10..15 zero), same swizzle as Kl
  {
    int rowp = tid >> 4, pc = tid & 15, lc = pc ^ (rowp & 7);
    short8 v = {0, 0, 0, 0, 0, 0, 0, 0};
    if (rowp < 10) v = *(const short8*)(PK + (long)rowp * 4096 + h * 128 + lc * 8);
    *(short8*)((char*)PKl + tid * 16) = v;
  }
  // stage prompt-V transposed [d][p] (cols 10..15 zero), 1-bit chunk swizzle
  {
    int d = tid >> 1, pb = (tid & 1) * 8;
#pragma unroll
    for (int e = 0; e < 8; e++) {
      int p = pb + e;
      short v = 0;
      if (p < 10) v = __builtin_bit_cast(short, PV[(long)p * 4096 + h * 128 + d]);
      *(short*)((char*)PVl + d * 32 + (((p >> 3) ^ (d & 1)) * 16) + (p & 7) * 2) = v;
    }
  }
  const float gate = GATE[h];

  f32x4 o[8];
#pragma unroll
  for (int i = 0; i < 8; i++) o[i] = (f32x4){0.f, 0.f, 0.f, 0.f};
  float m_[4] = {-1e30f, -1e30f, -1e30f, -1e30f};
  float l_[4] = {0.f, 0.f, 0.f, 0.f};

  const int nt = (qb + 1) * 2;
  const bf16* Kbase = Kg + ((long)b * 1024) * 4096 + h * 128;
  const bf16* Vbase = VT + ((long)bh) * 128 * 1024;
  const int cb1 = w * 64, cb2 = 256 + w * 64;
  const int iA = cb1 + l, iB = cb2 + l;
  bf16* pw = &Pl[w][0];

  for (int j = 0; j < nt; ++j) {
    __syncthreads();  // previous compute done before overwriting Kl/Vl
    {
      // K chunks: row = i>>4, phys chunk pc=i&15 holds logical lc = pc^(row&7)
      const bf16* gA = Kbase + (long)(j * 32 + (iA >> 4)) * 4096 + ((iA & 15) ^ ((iA >> 4) & 7)) * 8;
      const bf16* gB = Kbase + (long)(j * 32 + (iB >> 4)) * 4096 + ((iB & 15) ^ ((iB >> 4) & 7)) * 8;
      gl_lds16(gA, Kl + cb1 * 8);
      gl_lds16(gB, Kl + cb2 * 8);
      // V chunks: d = i>>2, phys pc=i&3 holds lc = pc^(d&3)
      const bf16* vA = Vbase + (long)(iA >> 2) * 1024 + j * 32 + ((iA & 3) ^ ((iA >> 2) & 3)) * 8;
      const bf16* vB = Vbase + (long)(iB >> 2) * 1024 + j * 32 + ((iB & 3) ^ ((iB >> 2) & 3)) * 8;
      gl_lds16(vA, Vl + cb1 * 8);
      gl_lds16(vB, Vl + cb2 * 8);
    }
    __syncthreads();

    // scores: 2 x 16-key sub-tiles
    f32x4 s[2];
#pragma unroll
    for (int ns = 0; ns < 2; ns++) {
      f32x4 a = (f32x4){0.f, 0.f, 0.f, 0.f};
      int krow = ns * 16 + lr;
      const char* kp = (const char*)Kl + krow * 256;
      int sw = krow & 7;
#pragma unroll
      for (int c = 0; c < 4; c++) {
        short8 kf = *(const short8*)(kp + (((c * 4 + lg) ^ sw) * 16));
        a = mfma16(qf[c], kf, a);
      }
      int key = j * 32 + krow;
#pragma unroll
      for (int r = 0; r < 4; r++) {
        int qr = q0 + lg * 4 + r;
        s[ns][r] = a[r] * SCALE_ + ((key <= qr) ? 0.0f : -1e30f);
      }
    }
    // online softmax (row-reduce over low-4 lane bits)
    float mx[4], cor[4], sum[4];
#pragma unroll
    for (int r = 0; r < 4; r++) mx[r] = fmaxf(s[0][r], s[1][r]);
#pragma unroll
    for (int xm = 1; xm < 16; xm <<= 1)
#pragma unroll
      for (int r = 0; r < 4; r++) mx[r] = fmaxf(mx[r], __shfl_xor(mx[r], xm, 64));
#pragma unroll
    for (int r = 0; r < 4; r++) {
      float mn = fmaxf(m_[r], mx[r]);
      cor[r] = __expf(m_[r] - mn);
      m_[r] = mn;
      s[0][r] = __expf(s[0][r] - mn);
      s[1][r] = __expf(s[1][r] - mn);
      sum[r] = s[0][r] + s[1][r];
    }
#pragma unroll
    for (int xm = 1; xm < 16; xm <<= 1)
#pragma unroll
      for (int r = 0; r < 4; r++) sum[r] += __shfl_xor(sum[r], xm, 64);
#pragma unroll
    for (int r = 0; r < 4; r++) l_[r] = l_[r] * cor[r] + sum[r];
#pragma unroll
    for (int df = 0; df < 8; df++)
#pragma unroll
      for (int r = 0; r < 4; r++) o[df][r] *= cor[r];

    // P (C-layout) -> per-wave LDS -> A-frag layout
#pragma unroll
    for (int ns = 0; ns < 2; ns++)
#pragma unroll
      for (int r = 0; r < 4; r++)
        *(short*)((char*)pw + ((lg * 4 + r) * 32 + ns * 16 + lr) * 2) = f2bf(s[ns][r]);
    asm volatile("s_waitcnt lgkmcnt(0)" ::: "memory");
    __builtin_amdgcn_sched_barrier(0);
    short8 pf = *(const short8*)(pw + lr * 32 + lg * 8);

    // PV: B-frags from transposed V tile (contiguous 16B reads)
#pragma unroll
    for (int df = 0; df < 8; df++) {
      int d = df * 16 + lr;
      short8 vf = *(const short8*)((const char*)Vl + d * 64 + ((lg ^ (d & 3)) * 16));
      o[df] = mfma16(pf, vf, o[df]);
    }
  }

  // ---- prompt attention (separate softmax, gated, unnormalized-by-l) ----
  f32x4 ps;
  {
    f32x4 a = (f32x4){0.f, 0.f, 0.f, 0.f};
    const char* kp = (const char*)PKl + lr * 256;
    int sw = lr & 7;
#pragma unroll
    for (int c = 0; c < 4; c++) {
      short8 kf = *(const short8*)(kp + (((c * 4 + lg) ^ sw) * 16));
      a = mfma16(qf[c], kf, a);
    }
#pragma unroll
    for (int r = 0; r < 4; r++) ps[r] = (lr < 10) ? a[r] * SCALE_ : -1e30f;
  }
  {
    float pm[4], pss[4];
#pragma unroll
    for (int r = 0; r < 4; r++) pm[r] = ps[r];
#pragma unroll
    for (int xm = 1; xm < 16; xm <<= 1)
#pragma unroll
      for (int r = 0; r < 4; r++) pm[r] = fmaxf(pm[r], __shfl_xor(pm[r], xm, 64));
#pragma unroll
    for (int r = 0; r < 4; r++) { ps[r] = __expf(ps[r] - pm[r]); pss[r] = ps[r]; }
#pragma unroll
    for (int xm = 1; xm < 16; xm <<= 1)
#pragma unroll
      for (int r = 0; r < 4; r++) pss[r] += __shfl_xor(pss[r], xm, 64);
#pragma unroll
    for (int r = 0; r < 4; r++) ps[r] = ps[r] / pss[r];
  }
#pragma unroll
  for (int r = 0; r < 4; r++) {
    *(short*)((char*)pw + ((lg * 4 + r) * 32 + lr) * 2) = f2bf(ps[r]);
    *(short*)((char*)pw + ((lg * 4 + r) * 32 + 16 + lr) * 2) = 0;
  }
  asm volatile("s_waitcnt lgkmcnt(0)" ::: "memory");
  __builtin_amdgcn_sched_barrier(0);
  short8 pf2 = *(const short8*)(pw + lr * 32 + lg * 8);
  f32x4 po[8];
#pragma unroll
  for (int df = 0; df < 8; df++) {
    int d = df * 16 + lr;
    short8 vf = {0, 0, 0, 0, 0, 0, 0, 0};
    if (lg < 2) vf = *(const short8*)((const char*)PVl + d * 32 + ((lg ^ (d & 1)) * 16));
    po[df] = mfma16(pf2, vf, (f32x4){0.f, 0.f, 0.f, 0.f});
  }

  // write: out[b][q][h][d]  (d_index = h*128 + d)
  bf16* op = O + ((long)(b * 1024 + q0 + lg * 4)) * 4096 + h * 128 + lr;
#pragma unroll
  for (int df = 0; df < 8; df++)
#pragma unroll
    for (int r = 0; r < 4; r++) {
      float val = o[df][r] / l_[r] + gate * po[df][r];
      *(short*)(op + (long)r * 4096 + df * 16) = f2bf(val);
    }
}

// ---------------------------------------------------------------------------
extern "C" void kernel_launch(void* const* d_in, const int* in_sizes, int n_in,
                              void* d_out, int out_size, void* d_ws, size_t ws_size,
                              hipStream_t stream) {
  (void)in_sizes; (void)n_in; (void)out_size; (void)ws_size;
  const float* x      = (const float*)d_in[0];
  const float* wq     = (const float*)d_in[1];
  const float* wk     = (const float*)d_in[2];
  const float* wv     = (const float*)d_in[3];
  const float* wo     = (const float*)d_in[4];
  const float* prompt = (const float*)d_in[5];
  const float* gate   = (const float*)d_in[6];
  const float* fcos   = (const float*)d_in[7];
  const float* fsin   = (const float*)d_in[8];
  // d_in[9] mask (causal, hardcoded), d_in[10] type_weight (unused), d_in[11] start_pos (=0)
  float* out = (float*)d_out;
  char* ws = (char*)d_ws;

  size_t o = 0;
  bf16* xb  = (bf16*)(ws + o); o += (size_t)8388608 * 2;    // x bf16
  bf16* wqb = (bf16*)(ws + o); o += (size_t)16777216 * 2;
  bf16* wkb = (bf16*)(ws + o); o += (size_t)16777216 * 2;
  bf16* wvb = (bf16*)(ws + o); o += (size_t)16777216 * 2;
  bf16* wob = (bf16*)(ws + o); o += (size_t)16777216 * 2;
  bf16* pb  = (bf16*)(ws + o); o += (size_t)40960 * 2;
  bf16* q_ws  = (bf16*)(ws + o); o += (size_t)2048 * 4096 * 2;
  bf16* k_ws  = (bf16*)(ws + o); o += (size_t)2048 * 4096 * 2;
  bf16* v_ws  = (bf16*)(ws + o); o += (size_t)2048 * 4096 * 2;
  bf16* vT_ws = (bf16*)(ws + o); o += (size_t)2048 * 4096 * 2;
  bf16* pk_ws = (bf16*)(ws + o); o += (size_t)40960 * 2;
  bf16* pv_ws = (bf16*)(ws + o); o += (size_t)40960 * 2;
  bf16* attn_ws = v_ws;  // raw v no longer needed after transpose

  // 1. downcast inputs to bf16 workspace
  cvt6<<<dim3(36884), 256, 0, stream>>>(x, wq, wk, wv, wo, prompt,
                                        xb, wqb, wkb, wvb, wob, pb);
  // 2. QKV (+prompt K/V rows 2048..2057) : 17 m-tiles, 32 n-tiles, z = q/k/v
  gemm_bt<<<dim3(17, 32, 3), 256, 0, stream>>>(
      xb, pb, wqb, wkb, wvb, q_ws, k_ws, v_ws, pk_ws, pv_ws, (float*)0, 2048, 2058);
  // 3. RoPE on q, k
  rope_qk<<<dim3(2048, 2), 256, 0, stream>>>(q_ws, k_ws, fcos, fsin);
  // 4. V -> VT
  transpose_v<<<dim3(16, 64), 256, 0, stream>>>(v_ws, vT_ws);
  // 5. flash attention + gated prompt attention
  flash_attn<<<dim3(16, 64), 256, 0, stream>>>(
      q_ws, k_ws, vT_ws, pk_ws, pv_ws, gate, attn_ws);
  // 6. output projection (f32 out)
  gemm_bt<<<dim3(16, 32, 1), 256, 0, stream>>>(
      attn_ws, (const bf16*)0, wob, wob, wob, q_ws, q_ws, q_ws,
      (bf16*)0, (bf16*)0, out, 2048, 2048);
}

// Round 3
// 566.439 us; speedup vs baseline: 1.2245x; 1.2245x over previous
//
#include <hip/hip_runtime.h>
#include <hip/hip_bf16.h>
#include <stdint.h>

typedef __hip_bfloat16 bf16;
typedef __attribute__((ext_vector_type(8))) short short8;
typedef __attribute__((ext_vector_type(4))) float f32x4;

#define SCALE_ 0.08838834764831845f  // 1/sqrt(128)

static __device__ __forceinline__ float bf2f(short u) {
  unsigned int x = ((unsigned int)(unsigned short)u) << 16;
  return __builtin_bit_cast(float, x);
}
static __device__ __forceinline__ short f2bf(float f) {
  __hip_bfloat16 h = __float2bfloat16(f);
  return __builtin_bit_cast(short, h);
}
static __device__ __forceinline__ f32x4 mfma16(short8 a, short8 b, f32x4 c) {
  return __builtin_amdgcn_mfma_f32_16x16x32_bf16(a, b, c, 0, 0, 0);
}
static __device__ __forceinline__ void gl_lds16(const bf16* g, bf16* l) {
  __builtin_amdgcn_global_load_lds(
      (const __attribute__((address_space(1))) unsigned int*)g,
      (__attribute__((address_space(3))) unsigned int*)l, 16, 0, 0);
}

// ---------------------------------------------------------------------------
// f32 -> bf16 conversion for x, wq, wk, wv, wo, prompt (one fused launch).
// ---------------------------------------------------------------------------
__global__ __launch_bounds__(256) void cvt6(
    const float* __restrict__ sx, const float* __restrict__ sq,
    const float* __restrict__ sk, const float* __restrict__ sv,
    const float* __restrict__ so, const float* __restrict__ sp,
    bf16* __restrict__ dx, bf16* __restrict__ dq, bf16* __restrict__ dk,
    bf16* __restrict__ dv, bf16* __restrict__ d4, bf16* __restrict__ dp)
{
  int b = blockIdx.x;
  const float* s; bf16* d; int off;
  if (b < 4096)       { s = sx; d = dx; off = b; }
  else if (b < 12288) { s = sq; d = dq; off = b - 4096; }
  else if (b < 20480) { s = sk; d = dk; off = b - 12288; }
  else if (b < 28672) { s = sv; d = dv; off = b - 20480; }
  else if (b < 36864) { s = so; d = d4; off = b - 28672; }
  else                { s = sp; d = dp; off = b - 36864; }
  long base = (long)off * 2048 + threadIdx.x * 8;
  f32x4 a = *(const f32x4*)(s + base);
  f32x4 c = *(const f32x4*)(s + base + 4);
  short8 o;
#pragma unroll
  for (int j = 0; j < 4; j++) { o[j] = f2bf(a[j]); o[4 + j] = f2bf(c[j]); }
  *(short8*)(d + base) = o;
}

// ---------------------------------------------------------------------------
// GEMM: C[m][n] = sum_k A[m][k] * Bw[n][k]  (A: MxK row-major, Bw: NxK row-major)
// 256x256 tile, BK=32, 8 waves (2m x 4n), per-wave 128x64 (8x4 frags).
// Double-buffered 64KB LDS, 1-deep global_load_lds prefetch, ONE s_barrier per
// K-step, counted waits (no __syncthreads -> no forced vmcnt(0)+lgkmcnt(0)
// mega-drain beyond what we place). XOR swizzle on 64B rows kills the 8-way
// bank conflict on ds_read_b128 (applied on global src; same XOR on read).
// Rows >= M1 come from A2 (prompt, clamped); outputs >= M1 go to Cp.
// CF != null -> f32 output (out-projection).
// ---------------------------------------------------------------------------
__global__ __launch_bounds__(512, 2) void gemm_bt(
    const bf16* __restrict__ A, const bf16* __restrict__ A2,
    const bf16* __restrict__ B0, const bf16* __restrict__ B1, const bf16* __restrict__ B2w,
    bf16* __restrict__ C0, bf16* __restrict__ C1, bf16* __restrict__ C2,
    bf16* __restrict__ P1, bf16* __restrict__ P2,
    float* __restrict__ CF,
    int M1, int Mtot)
{
  __shared__ char lds[65536];   // 2 bufs x (A 16KB + B 16KB)
  const int tid = threadIdx.x, w = tid >> 6, l = tid & 63;
  const int lr = l & 15, lg = l >> 4;
  const int wm = w >> 2, wn = w & 3;
  const int z = blockIdx.z;
  const bf16* Bw = (z == 0) ? B0 : ((z == 1) ? B1 : B2w);
  bf16* C  = (z == 0) ? C0 : ((z == 1) ? C1 : C2);
  bf16* Cp = (z == 0) ? (bf16*)0 : ((z == 1) ? P1 : P2);

  // T1: bijective chunked XCD swizzle (gridDim.x % 8 == 0), n fastest ->
  // each XCD works one A-panel row of n-tiles concurrently.
  const int cpx = gridDim.x >> 3, orig = blockIdx.x;
  const int wg = (orig & 7) * cpx + (orig >> 3);
  const long m0 = (long)(wg >> 4) * 256;
  const long n0 = (long)(wg & 15) * 256;

  // --- staging source pointers (2 A-chunks + 2 B-chunks per thread) ---
  // chunk id a in [0,1024): row = a>>2, phys col-chunk = a&3,
  // logical col-chunk cc = (a&3) ^ ((row>>1)&3) = (a&3) ^ ((a>>3)&3)
  const bf16 *aS0, *aS1, *bS0, *bS1;
  {
    int a0 = w * 64 + l, a1 = 512 + w * 64 + l;
    int r0 = a0 >> 2, r1 = a1 >> 2;
    int c0 = (a0 & 3) ^ ((a0 >> 3) & 3);
    int c1 = (a1 & 3) ^ ((a1 >> 3) & 3);
    long mx = (long)(Mtot - M1) - 1;
    long ra0 = m0 + r0, ra1 = m0 + r1;
    const bf16 *p0, *p1;
    if (ra0 < M1) p0 = A + ra0 * 4096;
    else { long rr = ra0 - M1; if (rr > mx) rr = mx; p0 = A2 + rr * 4096; }
    if (ra1 < M1) p1 = A + ra1 * 4096;
    else { long rr = ra1 - M1; if (rr > mx) rr = mx; p1 = A2 + rr * 4096; }
    aS0 = p0 + c0 * 8;
    aS1 = p1 + c1 * 8;
    bS0 = Bw + (n0 + r0) * 4096 + c0 * 8;
    bS1 = Bw + (n0 + r1) * 4096 + c1 * 8;
  }
  // frag-read swizzle offset (lane-constant: base rows are multiples of 16)
  const int fco = (lg ^ ((lr >> 1) & 3)) * 16;
  const int aoffL = (wm * 128 + lr) * 64 + fco;          // A frag base (bytes)
  const int boffL = 16384 + (wn * 64 + lr) * 64 + fco;   // B frag base (bytes)

  f32x4 acc[8][4];
#pragma unroll
  for (int i = 0; i < 8; i++)
#pragma unroll
    for (int j = 0; j < 4; j++) acc[i][j] = (f32x4){0.f, 0.f, 0.f, 0.f};

#define G_STAGE(TB_, T_)                                                     \
  {                                                                          \
    gl_lds16(aS0 + (T_) * 32, (bf16*)(lds + (TB_) * 32768 + w * 1024));      \
    gl_lds16(aS1 + (T_) * 32, (bf16*)(lds + (TB_) * 32768 + 8192 + w * 1024)); \
    gl_lds16(bS0 + (T_) * 32, (bf16*)(lds + (TB_) * 32768 + 16384 + w * 1024)); \
    gl_lds16(bS1 + (T_) * 32, (bf16*)(lds + (TB_) * 32768 + 24576 + w * 1024)); \
  }

#define G_ITER(T_, DO_STAGE_)                                                \
  {                                                                          \
    asm volatile("s_waitcnt vmcnt(0)" ::: "memory");                         \
    __builtin_amdgcn_s_barrier();                                            \
    __builtin_amdgcn_sched_barrier(0);                                       \
    if (DO_STAGE_) G_STAGE(((T_) + 1) & 1, (T_) + 1);                        \
    const char* base_ = lds + ((T_) & 1) * 32768;                            \
    short8 af_[8], bf_[4];                                                   \
    _Pragma("unroll") for (int mi = 0; mi < 8; mi++)                         \
      af_[mi] = *(const short8*)(base_ + aoffL + mi * 1024);                 \
    _Pragma("unroll") for (int ni = 0; ni < 4; ni++)                         \
      bf_[ni] = *(const short8*)(base_ + boffL + ni * 1024);                 \
    asm volatile("s_waitcnt lgkmcnt(0)" ::: "memory");                       \
    __builtin_amdgcn_sched_barrier(0);                                       \
    __builtin_amdgcn_s_setprio(1);                                           \
    _Pragma("unroll") for (int mi = 0; mi < 8; mi++)                         \
      _Pragma("unroll") for (int ni = 0; ni < 4; ni++)                       \
        acc[mi][ni] = mfma16(af_[mi], bf_[ni], acc[mi][ni]);                 \
    __builtin_amdgcn_s_setprio(0);                                           \
  }

  G_STAGE(0, 0);                 // prologue: tile 0 in flight
  for (int t = 0; t < 127; ++t)  // K/32 = 128 tiles
    G_ITER(t, 1);
  G_ITER(127, 0);

#undef G_ITER
#undef G_STAGE

  // epilogue: C/D layout col=lane&15, row=(lane>>4)*4+j
#pragma unroll
  for (int mi = 0; mi < 8; mi++) {
#pragma unroll
    for (int ni = 0; ni < 4; ni++) {
      long col = n0 + wn * 64 + ni * 16 + lr;
      f32x4 v = acc[mi][ni];
#pragma unroll
      for (int j = 0; j < 4; j++) {
        long row = m0 + wm * 128 + mi * 16 + lg * 4 + j;
        if (CF) {
          CF[row * 4096 + col] = v[j];
        } else if (row < M1) {
          *(short*)(C + row * 4096 + col) = f2bf(v[j]);
        } else if (Cp != 0 && row < Mtot) {
          *(short*)(Cp + (row - M1) * 4096 + col) = f2bf(v[j]);
        }
      }
    }
  }
}

// ---------------------------------------------------------------------------
// RoPE in-place on q / k  ([2048][4096]), freqs f32.
// ---------------------------------------------------------------------------
__global__ __launch_bounds__(256) void rope_qk(
    bf16* __restrict__ Q, bf16* __restrict__ Kb,
    const float* __restrict__ FC, const float* __restrict__ FS)
{
  const int row = blockIdx.x;
  const int s = row & 1023;
  const int t = threadIdx.x;
  bf16* base = (blockIdx.y ? Kb : Q) + (long)row * 4096 + t * 16;
  short8 v0 = *(const short8*)base;
  short8 v1 = *(const short8*)(base + 8);
  const float* cp = FC + s * 64 + (t & 7) * 8;
  const float* sp = FS + s * 64 + (t & 7) * 8;
  f32x4 c0 = *(const f32x4*)cp;
  f32x4 c1 = *(const f32x4*)(cp + 4);
  f32x4 s0 = *(const f32x4*)sp;
  f32x4 s1 = *(const f32x4*)(sp + 4);
  short8 o0, o1;
#pragma unroll
  for (int j = 0; j < 4; j++) {
    float c = c0[j], sn = s0[j];
    float e = bf2f(v0[2 * j]), od = bf2f(v0[2 * j + 1]);
    o0[2 * j] = f2bf(e * c - od * sn);
    o0[2 * j + 1] = f2bf(e * sn + od * c);
    float c2 = c1[j], sn2 = s1[j];
    float e2 = bf2f(v1[2 * j]), od2 = bf2f(v1[2 * j + 1]);
    o1[2 * j] = f2bf(e2 * c2 - od2 * sn2);
    o1[2 * j + 1] = f2bf(e2 * sn2 + od2 * c2);
  }
  *(short8*)base = o0;
  *(short8*)(base + 8) = o1;
}

// ---------------------------------------------------------------------------
// V transpose: v[b][s][h][d] -> vT[bh][d][s]
// ---------------------------------------------------------------------------
__global__ __launch_bounds__(256) void transpose_v(
    const bf16* __restrict__ V, bf16* __restrict__ VT)
{
  __shared__ bf16 T[64 * 128];
  const int tid = threadIdx.x;
  const int st = blockIdx.x * 64, bh = blockIdx.y;
  const int b = bh >> 5, h = bh & 31;
  const bf16* src = V + ((long)(b * 1024 + st)) * 4096 + h * 128;
#pragma unroll
  for (int rr = 0; rr < 4; ++rr) {
    int i = tid + rr * 256;
    int s_l = i >> 4, c = i & 15;
    short8 v = *(const short8*)(src + (long)s_l * 4096 + c * 8);
    *(short8*)((char*)T + s_l * 256 + ((c ^ (s_l & 7)) * 16)) = v;
  }
  __syncthreads();
#pragma unroll
  for (int rr = 0; rr < 4; ++rr) {
    int i = tid + rr * 256;
    int d = i >> 3, cs = i & 7;
    short8 ov;
#pragma unroll
    for (int e = 0; e < 8; e++) {
      int s_l = cs * 8 + e;
      ov[e] = *(const short*)((char*)T + s_l * 256 + (((d >> 3) ^ (s_l & 7)) * 16) + (d & 7) * 2);
    }
    *(short8*)(VT + ((long)bh * 128 + d) * 1024 + st + cs * 8) = ov;
  }
}

// ---------------------------------------------------------------------------
// Flash attention, causal, + fused gated prompt attention. (unchanged, passing)
// ---------------------------------------------------------------------------
__global__ __launch_bounds__(256) void flash_attn(
    const bf16* __restrict__ Q, const bf16* __restrict__ Kg, const bf16* __restrict__ VT,
    const bf16* __restrict__ PK, const bf16* __restrict__ PV,
    const float* __restrict__ GATE, bf16* __restrict__ O)
{
  __shared__ bf16 Kl[32 * 128];
  __shared__ bf16 Vl[128 * 32];
  __shared__ bf16 PKl[16 * 128];
  __shared__ bf16 PVl[128 * 16];
  __shared__ bf16 Pl[4][16 * 32];
  const int tid = threadIdx.x, w = tid >> 6, l = tid & 63;
  const int lg = l >> 4, lr = l & 15;
  const int qb = blockIdx.x, bh = blockIdx.y;
  const int b = bh >> 5, h = bh & 31;
  const int q0 = qb * 64 + w * 16;

  short8 qf[4];
  {
    const bf16* qp = Q + ((long)(b * 1024 + q0 + lr)) * 4096 + h * 128 + lg * 8;
#pragma unroll
    for (int c = 0; c < 4; c++) qf[c] = *(const short8*)(qp + c * 32);
  }
  {
    int rowp = tid >> 4, pc = tid & 15, lc = pc ^ (rowp & 7);
    short8 v = {0, 0, 0, 0, 0, 0, 0, 0};
    if (rowp < 10) v = *(const short8*)(PK + (long)rowp * 4096 + h * 128 + lc * 8);
    *(short8*)((char*)PKl + tid * 16) = v;
  }
  {
    int d = tid >> 1, pb = (tid & 1) * 8;
#pragma unroll
    for (int e = 0; e < 8; e++) {
      int p = pb + e;
      short v = 0;
      if (p < 10) v = __builtin_bit_cast(short, PV[(long)p * 4096 + h * 128 + d]);
      *(short*)((char*)PVl + d * 32 + (((p >> 3) ^ (d & 1)) * 16) + (p & 7) * 2) = v;
    }
  }
  const float gate = GATE[h];

  f32x4 o[8];
#pragma unroll
  for (int i = 0; i < 8; i++) o[i] = (f32x4){0.f, 0.f, 0.f, 0.f};
  float m_[4] = {-1e30f, -1e30f, -1e30f, -1e30f};
  float l_[4] = {0.f, 0.f, 0.f, 0.f};

  const int nt = (qb + 1) * 2;
  const bf16* Kbase = Kg + ((long)b * 1024) * 4096 + h * 128;
  const bf16* Vbase = VT + ((long)bh) * 128 * 1024;
  const int cb1 = w * 64, cb2 = 256 + w * 64;
  const int iA = cb1 + l, iB = cb2 + l;
  bf16* pw = &Pl[w][0];

  for (int j = 0; j < nt; ++j) {
    __syncthreads();
    {
      const bf16* gA = Kbase + (long)(j * 32 + (iA >> 4)) * 4096 + ((iA & 15) ^ ((iA >> 4) & 7)) * 8;
      const bf16* gB = Kbase + (long)(j * 32 + (iB >> 4)) * 4096 + ((iB & 15) ^ ((iB >> 4) & 7)) * 8;
      gl_lds16(gA, Kl + cb1 * 8);
      gl_lds16(gB, Kl + cb2 * 8);
      const bf16* vA = Vbase + (long)(iA >> 2) * 1024 + j * 32 + ((iA & 3) ^ ((iA >> 2) & 3)) * 8;
      const bf16* vB = Vbase + (long)(iB >> 2) * 1024 + j * 32 + ((iB & 3) ^ ((iB >> 2) & 3)) * 8;
      gl_lds16(vA, Vl + cb1 * 8);
      gl_lds16(vB, Vl + cb2 * 8);
    }
    __syncthreads();

    f32x4 s[2];
#pragma unroll
    for (int ns = 0; ns < 2; ns++) {
      f32x4 a = (f32x4){0.f, 0.f, 0.f, 0.f};
      int krow = ns * 16 + lr;
      const char* kp = (const char*)Kl + krow * 256;
      int sw = krow & 7;
#pragma unroll
      for (int c = 0; c < 4; c++) {
        short8 kf = *(const short8*)(kp + (((c * 4 + lg) ^ sw) * 16));
        a = mfma16(qf[c], kf, a);
      }
      int key = j * 32 + krow;
#pragma unroll
      for (int r = 0; r < 4; r++) {
        int qr = q0 + lg * 4 + r;
        s[ns][r] = a[r] * SCALE_ + ((key <= qr) ? 0.0f : -1e30f);
      }
    }
    float mx[4], cor[4], sum[4];
#pragma unroll
    for (int r = 0; r < 4; r++) mx[r] = fmaxf(s[0][r], s[1][r]);
#pragma unroll
    for (int xm = 1; xm < 16; xm <<= 1)
#pragma unroll
      for (int r = 0; r < 4; r++) mx[r] = fmaxf(mx[r], __shfl_xor(mx[r], xm, 64));
#pragma unroll
    for (int r = 0; r < 4; r++) {
      float mn = fmaxf(m_[r], mx[r]);
      cor[r] = __expf(m_[r] - mn);
      m_[r] = mn;
      s[0][r] = __expf(s[0][r] - mn);
      s[1][r] = __expf(s[1][r] - mn);
      sum[r] = s[0][r] + s[1][r];
    }
#pragma unroll
    for (int xm = 1; xm < 16; xm <<= 1)
#pragma unroll
      for (int r = 0; r < 4; r++) sum[r] += __shfl_xor(sum[r], xm, 64);
#pragma unroll
    for (int r = 0; r < 4; r++) l_[r] = l_[r] * cor[r] + sum[r];
#pragma unroll
    for (int df = 0; df < 8; df++)
#pragma unroll
      for (int r = 0; r < 4; r++) o[df][r] *= cor[r];

#pragma unroll
    for (int ns = 0; ns < 2; ns++)
#pragma unroll
      for (int r = 0; r < 4; r++)
        *(short*)((char*)pw + ((lg * 4 + r) * 32 + ns * 16 + lr) * 2) = f2bf(s[ns][r]);
    asm volatile("s_waitcnt lgkmcnt(0)" ::: "memory");
    __builtin_amdgcn_sched_barrier(0);
    short8 pf = *(const short8*)(pw + lr * 32 + lg * 8);

#pragma unroll
    for (int df = 0; df < 8; df++) {
      int d = df * 16 + lr;
      short8 vf = *(const short8*)((const char*)Vl + d * 64 + ((lg ^ (d & 3)) * 16));
      o[df] = mfma16(pf, vf, o[df]);
    }
  }

  // ---- prompt attention ----
  f32x4 ps;
  {
    f32x4 a = (f32x4){0.f, 0.f, 0.f, 0.f};
    const char* kp = (const char*)PKl + lr * 256;
    int sw = lr & 7;
#pragma unroll
    for (int c = 0; c < 4; c++) {
      short8 kf = *(const short8*)(kp + (((c * 4 + lg) ^ sw) * 16));
      a = mfma16(qf[c], kf, a);
    }
#pragma unroll
    for (int r = 0; r < 4; r++) ps[r] = (lr < 10) ? a[r] * SCALE_ : -1e30f;
  }
  {
    float pm[4], pss[4];
#pragma unroll
    for (int r = 0; r < 4; r++) pm[r] = ps[r];
#pragma unroll
    for (int xm = 1; xm < 16; xm <<= 1)
#pragma unroll
      for (int r = 0; r < 4; r++) pm[r] = fmaxf(pm[r], __shfl_xor(pm[r], xm, 64));
#pragma unroll
    for (int r = 0; r < 4; r++) { ps[r] = __expf(ps[r] - pm[r]); pss[r] = ps[r]; }
#pragma unroll
    for (int xm = 1; xm < 16; xm <<= 1)
#pragma unroll
      for (int r = 0; r < 4; r++) pss[r] += __shfl_xor(pss[r], xm, 64);
#pragma unroll
    for (int r = 0; r < 4; r++) ps[r] = ps[r] / pss[r];
  }
#pragma unroll
  for (int r = 0; r < 4; r++) {
    *(short*)((char*)pw + ((lg * 4 + r) * 32 + lr) * 2) = f2bf(ps[r]);
    *(short*)((char*)pw + ((lg * 4 + r) * 32 + 16 + lr) * 2) = 0;
  }
  asm volatile("s_waitcnt lgkmcnt(0)" ::: "memory");
  __builtin_amdgcn_sched_barrier(0);
  short8 pf2 = *(const short8*)(pw + lr * 32 + lg * 8);
  f32x4 po[8];
#pragma unroll
  for (int df = 0; df < 8; df++) {
    int d = df * 16 + lr;
    short8 vf = {0, 0, 0, 0, 0, 0, 0, 0};
    if (lg < 2) vf = *(const short8*)((const char*)PVl + d * 32 + ((lg ^ (d & 1)) * 16));
    po[df] = mfma16(pf2, vf, (f32x4){0.f, 0.f, 0.f, 0.f});
  }

  bf16* op = O + ((long)(b * 1024 + q0 + lg * 4)) * 4096 + h * 128 + lr;
#pragma unroll
  for (int df = 0; df < 8; df++)
#pragma unroll
    for (int r = 0; r < 4; r++) {
      float val = o[df][r] / l_[r] + gate * po[df][r];
      *(short*)(op + (long)r * 4096 + df * 16) = f2bf(val);
    }
}

// ---------------------------------------------------------------------------
extern "C" void kernel_launch(void* const* d_in, const int* in_sizes, int n_in,
                              void* d_out, int out_size, void* d_ws, size_t ws_size,
                              hipStream_t stream) {
  (void)in_sizes; (void)n_in; (void)out_size; (void)ws_size;
  const float* x      = (const float*)d_in[0];
  const float* wq     = (const float*)d_in[1];
  const float* wk     = (const float*)d_in[2];
  const float* wv     = (const float*)d_in[3];
  const float* wo     = (const float*)d_in[4];
  const float* prompt = (const float*)d_in[5];
  const float* gate   = (const float*)d_in[6];
  const float* fcos   = (const float*)d_in[7];
  const float* fsin   = (const float*)d_in[8];
  float* out = (float*)d_out;
  char* ws = (char*)d_ws;

  size_t o = 0;
  bf16* xb  = (bf16*)(ws + o); o += (size_t)8388608 * 2;
  bf16* wqb = (bf16*)(ws + o); o += (size_t)16777216 * 2;
  bf16* wkb = (bf16*)(ws + o); o += (size_t)16777216 * 2;
  bf16* wvb = (bf16*)(ws + o); o += (size_t)16777216 * 2;
  bf16* wob = (bf16*)(ws + o); o += (size_t)16777216 * 2;
  bf16* pb  = (bf16*)(ws + o); o += (size_t)40960 * 2;
  bf16* q_ws  = (bf16*)(ws + o); o += (size_t)2048 * 4096 * 2;
  bf16* k_ws  = (bf16*)(ws + o); o += (size_t)2048 * 4096 * 2;
  bf16* v_ws  = (bf16*)(ws + o); o += (size_t)2048 * 4096 * 2;
  bf16* vT_ws = (bf16*)(ws + o); o += (size_t)2048 * 4096 * 2;
  bf16* pk_ws = (bf16*)(ws + o); o += (size_t)40960 * 2;
  bf16* pv_ws = (bf16*)(ws + o); o += (size_t)40960 * 2;
  bf16* attn_ws = v_ws;

  // 1. downcast inputs to bf16
  cvt6<<<dim3(36884), 256, 0, stream>>>(x, wq, wk, wv, wo, prompt,
                                        xb, wqb, wkb, wvb, wob, pb);
  // 2. QKV (+prompt K/V rows): 9 m-tiles x 16 n-tiles per z (144 % 8 == 0)
  gemm_bt<<<dim3(144, 1, 3), 512, 0, stream>>>(
      xb, pb, wqb, wkb, wvb, q_ws, k_ws, v_ws, pk_ws, pv_ws, (float*)0, 2048, 2058);
  // 3. RoPE on q, k
  rope_qk<<<dim3(2048, 2), 256, 0, stream>>>(q_ws, k_ws, fcos, fsin);
  // 4. V -> VT
  transpose_v<<<dim3(16, 64), 256, 0, stream>>>(v_ws, vT_ws);
  // 5. flash attention + gated prompt attention
  flash_attn<<<dim3(16, 64), 256, 0, stream>>>(
      q_ws, k_ws, vT_ws, pk_ws, pv_ws, gate, attn_ws);
  // 6. output projection (f32 out): 8 x 16 tiles (128 % 8 == 0)
  gemm_bt<<<dim3(128, 1, 1), 512, 0, stream>>>(
      attn_ws, (const bf16*)0, wob, wob, wob, q_ws, q_ws, q_ws,
      (bf16*)0, (bf16*)0, out, 2048, 2048);
}

// Round 4
// 544.884 us; speedup vs baseline: 1.2729x; 1.0396x over previous
//
#include <hip/hip_runtime.h>
#include <hip/hip_bf16.h>
#include <stdint.h>

typedef __hip_bfloat16 bf16;
typedef __attribute__((ext_vector_type(8))) short short8;
typedef __attribute__((ext_vector_type(4))) float f32x4;

#define SCALE_ 0.08838834764831845f  // 1/sqrt(128)

static __device__ __forceinline__ float bf2f(short u) {
  unsigned int x = ((unsigned int)(unsigned short)u) << 16;
  return __builtin_bit_cast(float, x);
}
static __device__ __forceinline__ short f2bf(float f) {
  __hip_bfloat16 h = __float2bfloat16(f);
  return __builtin_bit_cast(short, h);
}
static __device__ __forceinline__ f32x4 mfma16(short8 a, short8 b, f32x4 c) {
  return __builtin_amdgcn_mfma_f32_16x16x32_bf16(a, b, c, 0, 0, 0);
}
static __device__ __forceinline__ void gl_lds16(const bf16* g, bf16* l) {
  __builtin_amdgcn_global_load_lds(
      (const __attribute__((address_space(1))) unsigned int*)g,
      (__attribute__((address_space(3))) unsigned int*)l, 16, 0, 0);
}

// ---------------------------------------------------------------------------
// f32 -> bf16 conversion for x, wq, wk, wv, wo, prompt (one fused launch).
// ---------------------------------------------------------------------------
__global__ __launch_bounds__(256) void cvt6(
    const float* __restrict__ sx, const float* __restrict__ sq,
    const float* __restrict__ sk, const float* __restrict__ sv,
    const float* __restrict__ so, const float* __restrict__ sp,
    bf16* __restrict__ dx, bf16* __restrict__ dq, bf16* __restrict__ dk,
    bf16* __restrict__ dv, bf16* __restrict__ d4, bf16* __restrict__ dp)
{
  int b = blockIdx.x;
  const float* s; bf16* d; int off;
  if (b < 4096)       { s = sx; d = dx; off = b; }
  else if (b < 12288) { s = sq; d = dq; off = b - 4096; }
  else if (b < 20480) { s = sk; d = dk; off = b - 12288; }
  else if (b < 28672) { s = sv; d = dv; off = b - 20480; }
  else if (b < 36864) { s = so; d = d4; off = b - 28672; }
  else                { s = sp; d = dp; off = b - 36864; }
  long base = (long)off * 2048 + threadIdx.x * 8;
  f32x4 a = *(const f32x4*)(s + base);
  f32x4 c = *(const f32x4*)(s + base + 4);
  short8 o;
#pragma unroll
  for (int j = 0; j < 4; j++) { o[j] = f2bf(a[j]); o[4 + j] = f2bf(c[j]); }
  *(short8*)(d + base) = o;
}

// ---------------------------------------------------------------------------
// GEMM: C[m][n] = sum_k A[m][k] * Bw[n][k]  (A: MxK row-major, Bw: NxK row-major)
// 256x256 tile, BK=32, 8 waves (2m x 4n), per-wave 128x64 (8x4 frags).
// 4-buffer LDS (128 KiB), DEPTH-3 global_load_lds prefetch with counted
// vmcnt(8) steady-state (T4: never drain to 0 in main loop), ONE s_barrier
// per K-step. Race-freedom: each wave's vmcnt(N) + following barrier makes
// the oldest tile's loads collectively visible; buffer (t+3)&3 was last read
// in iter t-1, and every wave finished those reads before crossing barrier t,
// which precedes any wave's stage-issue of tile t+3.
// XOR swizzle on 64B rows kills bank conflicts (pre-applied on global src).
// Rows >= M1 come from A2 (prompt, clamped); outputs >= M1 go to Cp.
// CF != null -> f32 output (out-projection).
// ---------------------------------------------------------------------------
__global__ __launch_bounds__(512, 2) void gemm_bt(
    const bf16* __restrict__ A, const bf16* __restrict__ A2,
    const bf16* __restrict__ B0, const bf16* __restrict__ B1, const bf16* __restrict__ B2w,
    bf16* __restrict__ C0, bf16* __restrict__ C1, bf16* __restrict__ C2,
    bf16* __restrict__ P1, bf16* __restrict__ P2,
    float* __restrict__ CF,
    int M1, int Mtot)
{
  __shared__ char lds[131072];   // 4 bufs x (A 16KB + B 16KB)
  const int tid = threadIdx.x, w = tid >> 6, l = tid & 63;
  const int lr = l & 15, lg = l >> 4;
  const int wm = w >> 2, wn = w & 3;
  const int z = blockIdx.z;
  const bf16* Bw = (z == 0) ? B0 : ((z == 1) ? B1 : B2w);
  bf16* C  = (z == 0) ? C0 : ((z == 1) ? C1 : C2);
  bf16* Cp = (z == 0) ? (bf16*)0 : ((z == 1) ? P1 : P2);

  // T1: bijective chunked XCD swizzle (gridDim.x % 8 == 0), n fastest.
  const int cpx = gridDim.x >> 3, orig = blockIdx.x;
  const int wg = (orig & 7) * cpx + (orig >> 3);
  const long m0 = (long)(wg >> 4) * 256;
  const long n0 = (long)(wg & 15) * 256;

  // staging source pointers (2 A-chunks + 2 B-chunks per thread)
  // chunk id a: row = a>>2, logical col-chunk = (a&3) ^ ((a>>3)&3)
  const bf16 *aS0, *aS1, *bS0, *bS1;
  {
    int a0 = w * 64 + l, a1 = 512 + w * 64 + l;
    int r0 = a0 >> 2, r1 = a1 >> 2;
    int c0 = (a0 & 3) ^ ((a0 >> 3) & 3);
    int c1 = (a1 & 3) ^ ((a1 >> 3) & 3);
    long mx = (long)(Mtot - M1) - 1;
    long ra0 = m0 + r0, ra1 = m0 + r1;
    const bf16 *p0, *p1;
    if (ra0 < M1) p0 = A + ra0 * 4096;
    else { long rr = ra0 - M1; if (rr > mx) rr = mx; p0 = A2 + rr * 4096; }
    if (ra1 < M1) p1 = A + ra1 * 4096;
    else { long rr = ra1 - M1; if (rr > mx) rr = mx; p1 = A2 + rr * 4096; }
    aS0 = p0 + c0 * 8;
    aS1 = p1 + c1 * 8;
    bS0 = Bw + (n0 + r0) * 4096 + c0 * 8;
    bS1 = Bw + (n0 + r1) * 4096 + c1 * 8;
  }
  // frag-read swizzle offset (lane-constant: base rows are multiples of 16)
  const int fco = (lg ^ ((lr >> 1) & 3)) * 16;
  const int aoffL = (wm * 128 + lr) * 64 + fco;          // A frag base (bytes)
  const int boffL = 16384 + (wn * 64 + lr) * 64 + fco;   // B frag base (bytes)

  f32x4 acc[8][4];
#pragma unroll
  for (int i = 0; i < 8; i++)
#pragma unroll
    for (int j = 0; j < 4; j++) acc[i][j] = (f32x4){0.f, 0.f, 0.f, 0.f};

#define G_STAGE(TB_, T_)                                                       \
  {                                                                            \
    char* bb_ = lds + (TB_) * 32768;                                           \
    gl_lds16(aS0 + (T_) * 32, (bf16*)(bb_ + w * 1024));                        \
    gl_lds16(aS1 + (T_) * 32, (bf16*)(bb_ + 8192 + w * 1024));                 \
    gl_lds16(bS0 + (T_) * 32, (bf16*)(bb_ + 16384 + w * 1024));                \
    gl_lds16(bS1 + (T_) * 32, (bf16*)(bb_ + 24576 + w * 1024));                \
  }

#define G_BODY(T_, DO_STAGE_)                                                  \
  {                                                                            \
    __builtin_amdgcn_s_barrier();                                              \
    __builtin_amdgcn_sched_barrier(0);                                         \
    if (DO_STAGE_) G_STAGE(((T_) + 3) & 3, (T_) + 3);                          \
    const char* base_ = lds + (((T_) & 3) * 32768);                            \
    short8 af_[8], bf_[4];                                                     \
    _Pragma("unroll") for (int mi = 0; mi < 8; mi++)                           \
      af_[mi] = *(const short8*)(base_ + aoffL + mi * 1024);                   \
    _Pragma("unroll") for (int ni = 0; ni < 4; ni++)                           \
      bf_[ni] = *(const short8*)(base_ + boffL + ni * 1024);                   \
    asm volatile("s_waitcnt lgkmcnt(0)" ::: "memory");                         \
    __builtin_amdgcn_sched_barrier(0);                                         \
    __builtin_amdgcn_s_setprio(1);                                             \
    _Pragma("unroll") for (int mi = 0; mi < 8; mi++)                           \
      _Pragma("unroll") for (int ni = 0; ni < 4; ni++)                         \
        acc[mi][ni] = mfma16(af_[mi], bf_[ni], acc[mi][ni]);                   \
    __builtin_amdgcn_s_setprio(0);                                             \
  }

  // prologue: 3 tiles in flight (12 loads)
  G_STAGE(0, 0);
  G_STAGE(1, 1);
  G_STAGE(2, 2);
  // main loop: steady state 12 loads in flight; wait oldest tile -> vmcnt(8)
  for (int t = 0; t < 125; ++t) {
    asm volatile("s_waitcnt vmcnt(8)" ::: "memory");
    G_BODY(t, 1);
  }
  // epilogue drain: 125 (12 in flight), 126 (8), 127 (4)
  asm volatile("s_waitcnt vmcnt(8)" ::: "memory");
  G_BODY(125, 0);
  asm volatile("s_waitcnt vmcnt(4)" ::: "memory");
  G_BODY(126, 0);
  asm volatile("s_waitcnt vmcnt(0)" ::: "memory");
  G_BODY(127, 0);

#undef G_BODY
#undef G_STAGE

  // epilogue: C/D layout col=lane&15, row=(lane>>4)*4+j
#pragma unroll
  for (int mi = 0; mi < 8; mi++) {
#pragma unroll
    for (int ni = 0; ni < 4; ni++) {
      long col = n0 + wn * 64 + ni * 16 + lr;
      f32x4 v = acc[mi][ni];
#pragma unroll
      for (int j = 0; j < 4; j++) {
        long row = m0 + wm * 128 + mi * 16 + lg * 4 + j;
        if (CF) {
          CF[row * 4096 + col] = v[j];
        } else if (row < M1) {
          *(short*)(C + row * 4096 + col) = f2bf(v[j]);
        } else if (Cp != 0 && row < Mtot) {
          *(short*)(Cp + (row - M1) * 4096 + col) = f2bf(v[j]);
        }
      }
    }
  }
}

// ---------------------------------------------------------------------------
// RoPE in-place on q / k  ([2048][4096]), freqs f32.
// ---------------------------------------------------------------------------
__global__ __launch_bounds__(256) void rope_qk(
    bf16* __restrict__ Q, bf16* __restrict__ Kb,
    const float* __restrict__ FC, const float* __restrict__ FS)
{
  const int row = blockIdx.x;
  const int s = row & 1023;
  const int t = threadIdx.x;
  bf16* base = (blockIdx.y ? Kb : Q) + (long)row * 4096 + t * 16;
  short8 v0 = *(const short8*)base;
  short8 v1 = *(const short8*)(base + 8);
  const float* cp = FC + s * 64 + (t & 7) * 8;
  const float* sp = FS + s * 64 + (t & 7) * 8;
  f32x4 c0 = *(const f32x4*)cp;
  f32x4 c1 = *(const f32x4*)(cp + 4);
  f32x4 s0 = *(const f32x4*)sp;
  f32x4 s1 = *(const f32x4*)(sp + 4);
  short8 o0, o1;
#pragma unroll
  for (int j = 0; j < 4; j++) {
    float c = c0[j], sn = s0[j];
    float e = bf2f(v0[2 * j]), od = bf2f(v0[2 * j + 1]);
    o0[2 * j] = f2bf(e * c - od * sn);
    o0[2 * j + 1] = f2bf(e * sn + od * c);
    float c2 = c1[j], sn2 = s1[j];
    float e2 = bf2f(v1[2 * j]), od2 = bf2f(v1[2 * j + 1]);
    o1[2 * j] = f2bf(e2 * c2 - od2 * sn2);
    o1[2 * j + 1] = f2bf(e2 * sn2 + od2 * c2);
  }
  *(short8*)base = o0;
  *(short8*)(base + 8) = o1;
}

// ---------------------------------------------------------------------------
// V transpose: v[b][s][h][d] -> vT[bh][d][s]
// ---------------------------------------------------------------------------
__global__ __launch_bounds__(256) void transpose_v(
    const bf16* __restrict__ V, bf16* __restrict__ VT)
{
  __shared__ bf16 T[64 * 128];
  const int tid = threadIdx.x;
  const int st = blockIdx.x * 64, bh = blockIdx.y;
  const int b = bh >> 5, h = bh & 31;
  const bf16* src = V + ((long)(b * 1024 + st)) * 4096 + h * 128;
#pragma unroll
  for (int rr = 0; rr < 4; ++rr) {
    int i = tid + rr * 256;
    int s_l = i >> 4, c = i & 15;
    short8 v = *(const short8*)(src + (long)s_l * 4096 + c * 8);
    *(short8*)((char*)T + s_l * 256 + ((c ^ (s_l & 7)) * 16)) = v;
  }
  __syncthreads();
#pragma unroll
  for (int rr = 0; rr < 4; ++rr) {
    int i = tid + rr * 256;
    int d = i >> 3, cs = i & 7;
    short8 ov;
#pragma unroll
    for (int e = 0; e < 8; e++) {
      int s_l = cs * 8 + e;
      ov[e] = *(const short*)((char*)T + s_l * 256 + (((d >> 3) ^ (s_l & 7)) * 16) + (d & 7) * 2);
    }
    *(short8*)(VT + ((long)bh * 128 + d) * 1024 + st + cs * 8) = ov;
  }
}

// ---------------------------------------------------------------------------
// Flash attention, causal, + fused gated prompt attention. (unchanged, passing)
// ---------------------------------------------------------------------------
__global__ __launch_bounds__(256) void flash_attn(
    const bf16* __restrict__ Q, const bf16* __restrict__ Kg, const bf16* __restrict__ VT,
    const bf16* __restrict__ PK, const bf16* __restrict__ PV,
    const float* __restrict__ GATE, bf16* __restrict__ O)
{
  __shared__ bf16 Kl[32 * 128];
  __shared__ bf16 Vl[128 * 32];
  __shared__ bf16 PKl[16 * 128];
  __shared__ bf16 PVl[128 * 16];
  __shared__ bf16 Pl[4][16 * 32];
  const int tid = threadIdx.x, w = tid >> 6, l = tid & 63;
  const int lg = l >> 4, lr = l & 15;
  const int qb = blockIdx.x, bh = blockIdx.y;
  const int b = bh >> 5, h = bh & 31;
  const int q0 = qb * 64 + w * 16;

  short8 qf[4];
  {
    const bf16* qp = Q + ((long)(b * 1024 + q0 + lr)) * 4096 + h * 128 + lg * 8;
#pragma unroll
    for (int c = 0; c < 4; c++) qf[c] = *(const short8*)(qp + c * 32);
  }
  {
    int rowp = tid >> 4, pc = tid & 15, lc = pc ^ (rowp & 7);
    short8 v = {0, 0, 0, 0, 0, 0, 0, 0};
    if (rowp < 10) v = *(const short8*)(PK + (long)rowp * 4096 + h * 128 + lc * 8);
    *(short8*)((char*)PKl + tid * 16) = v;
  }
  {
    int d = tid >> 1, pb = (tid & 1) * 8;
#pragma unroll
    for (int e = 0; e < 8; e++) {
      int p = pb + e;
      short v = 0;
      if (p < 10) v = __builtin_bit_cast(short, PV[(long)p * 4096 + h * 128 + d]);
      *(short*)((char*)PVl + d * 32 + (((p >> 3) ^ (d & 1)) * 16) + (p & 7) * 2) = v;
    }
  }
  const float gate = GATE[h];

  f32x4 o[8];
#pragma unroll
  for (int i = 0; i < 8; i++) o[i] = (f32x4){0.f, 0.f, 0.f, 0.f};
  float m_[4] = {-1e30f, -1e30f, -1e30f, -1e30f};
  float l_[4] = {0.f, 0.f, 0.f, 0.f};

  const int nt = (qb + 1) * 2;
  const bf16* Kbase = Kg + ((long)b * 1024) * 4096 + h * 128;
  const bf16* Vbase = VT + ((long)bh) * 128 * 1024;
  const int cb1 = w * 64, cb2 = 256 + w * 64;
  const int iA = cb1 + l, iB = cb2 + l;
  bf16* pw = &Pl[w][0];

  for (int j = 0; j < nt; ++j) {
    __syncthreads();
    {
      const bf16* gA = Kbase + (long)(j * 32 + (iA >> 4)) * 4096 + ((iA & 15) ^ ((iA >> 4) & 7)) * 8;
      const bf16* gB = Kbase + (long)(j * 32 + (iB >> 4)) * 4096 + ((iB & 15) ^ ((iB >> 4) & 7)) * 8;
      gl_lds16(gA, Kl + cb1 * 8);
      gl_lds16(gB, Kl + cb2 * 8);
      const bf16* vA = Vbase + (long)(iA >> 2) * 1024 + j * 32 + ((iA & 3) ^ ((iA >> 2) & 3)) * 8;
      const bf16* vB = Vbase + (long)(iB >> 2) * 1024 + j * 32 + ((iB & 3) ^ ((iB >> 2) & 3)) * 8;
      gl_lds16(vA, Vl + cb1 * 8);
      gl_lds16(vB, Vl + cb2 * 8);
    }
    __syncthreads();

    f32x4 s[2];
#pragma unroll
    for (int ns = 0; ns < 2; ns++) {
      f32x4 a = (f32x4){0.f, 0.f, 0.f, 0.f};
      int krow = ns * 16 + lr;
      const char* kp = (const char*)Kl + krow * 256;
      int sw = krow & 7;
#pragma unroll
      for (int c = 0; c < 4; c++) {
        short8 kf = *(const short8*)(kp + (((c * 4 + lg) ^ sw) * 16));
        a = mfma16(qf[c], kf, a);
      }
      int key = j * 32 + krow;
#pragma unroll
      for (int r = 0; r < 4; r++) {
        int qr = q0 + lg * 4 + r;
        s[ns][r] = a[r] * SCALE_ + ((key <= qr) ? 0.0f : -1e30f);
      }
    }
    float mx[4], cor[4], sum[4];
#pragma unroll
    for (int r = 0; r < 4; r++) mx[r] = fmaxf(s[0][r], s[1][r]);
#pragma unroll
    for (int xm = 1; xm < 16; xm <<= 1)
#pragma unroll
      for (int r = 0; r < 4; r++) mx[r] = fmaxf(mx[r], __shfl_xor(mx[r], xm, 64));
#pragma unroll
    for (int r = 0; r < 4; r++) {
      float mn = fmaxf(m_[r], mx[r]);
      cor[r] = __expf(m_[r] - mn);
      m_[r] = mn;
      s[0][r] = __expf(s[0][r] - mn);
      s[1][r] = __expf(s[1][r] - mn);
      sum[r] = s[0][r] + s[1][r];
    }
#pragma unroll
    for (int xm = 1; xm < 16; xm <<= 1)
#pragma unroll
      for (int r = 0; r < 4; r++) sum[r] += __shfl_xor(sum[r], xm, 64);
#pragma unroll
    for (int r = 0; r < 4; r++) l_[r] = l_[r] * cor[r] + sum[r];
#pragma unroll
    for (int df = 0; df < 8; df++)
#pragma unroll
      for (int r = 0; r < 4; r++) o[df][r] *= cor[r];

#pragma unroll
    for (int ns = 0; ns < 2; ns++)
#pragma unroll
      for (int r = 0; r < 4; r++)
        *(short*)((char*)pw + ((lg * 4 + r) * 32 + ns * 16 + lr) * 2) = f2bf(s[ns][r]);
    asm volatile("s_waitcnt lgkmcnt(0)" ::: "memory");
    __builtin_amdgcn_sched_barrier(0);
    short8 pf = *(const short8*)(pw + lr * 32 + lg * 8);

#pragma unroll
    for (int df = 0; df < 8; df++) {
      int d = df * 16 + lr;
      short8 vf = *(const short8*)((const char*)Vl + d * 64 + ((lg ^ (d & 3)) * 16));
      o[df] = mfma16(pf, vf, o[df]);
    }
  }

  // ---- prompt attention ----
  f32x4 ps;
  {
    f32x4 a = (f32x4){0.f, 0.f, 0.f, 0.f};
    const char* kp = (const char*)PKl + lr * 256;
    int sw = lr & 7;
#pragma unroll
    for (int c = 0; c < 4; c++) {
      short8 kf = *(const short8*)(kp + (((c * 4 + lg) ^ sw) * 16));
      a = mfma16(qf[c], kf, a);
    }
#pragma unroll
    for (int r = 0; r < 4; r++) ps[r] = (lr < 10) ? a[r] * SCALE_ : -1e30f;
  }
  {
    float pm[4], pss[4];
#pragma unroll
    for (int r = 0; r < 4; r++) pm[r] = ps[r];
#pragma unroll
    for (int xm = 1; xm < 16; xm <<= 1)
#pragma unroll
      for (int r = 0; r < 4; r++) pm[r] = fmaxf(pm[r], __shfl_xor(pm[r], xm, 64));
#pragma unroll
    for (int r = 0; r < 4; r++) { ps[r] = __expf(ps[r] - pm[r]); pss[r] = ps[r]; }
#pragma unroll
    for (int xm = 1; xm < 16; xm <<= 1)
#pragma unroll
      for (int r = 0; r < 4; r++) pss[r] += __shfl_xor(pss[r], xm, 64);
#pragma unroll
    for (int r = 0; r < 4; r++) ps[r] = ps[r] / pss[r];
  }
#pragma unroll
  for (int r = 0; r < 4; r++) {
    *(short*)((char*)pw + ((lg * 4 + r) * 32 + lr) * 2) = f2bf(ps[r]);
    *(short*)((char*)pw + ((lg * 4 + r) * 32 + 16 + lr) * 2) = 0;
  }
  asm volatile("s_waitcnt lgkmcnt(0)" ::: "memory");
  __builtin_amdgcn_sched_barrier(0);
  short8 pf2 = *(const short8*)(pw + lr * 32 + lg * 8);
  f32x4 po[8];
#pragma unroll
  for (int df = 0; df < 8; df++) {
    int d = df * 16 + lr;
    short8 vf = {0, 0, 0, 0, 0, 0, 0, 0};
    if (lg < 2) vf = *(const short8*)((const char*)PVl + d * 32 + ((lg ^ (d & 1)) * 16));
    po[df] = mfma16(pf2, vf, (f32x4){0.f, 0.f, 0.f, 0.f});
  }

  bf16* op = O + ((long)(b * 1024 + q0 + lg * 4)) * 4096 + h * 128 + lr;
#pragma unroll
  for (int df = 0; df < 8; df++)
#pragma unroll
    for (int r = 0; r < 4; r++) {
      float val = o[df][r] / l_[r] + gate * po[df][r];
      *(short*)(op + (long)r * 4096 + df * 16) = f2bf(val);
    }
}

// ---------------------------------------------------------------------------
extern "C" void kernel_launch(void* const* d_in, const int* in_sizes, int n_in,
                              void* d_out, int out_size, void* d_ws, size_t ws_size,
                              hipStream_t stream) {
  (void)in_sizes; (void)n_in; (void)out_size; (void)ws_size;
  const float* x      = (const float*)d_in[0];
  const float* wq     = (const float*)d_in[1];
  const float* wk     = (const float*)d_in[2];
  const float* wv     = (const float*)d_in[3];
  const float* wo     = (const float*)d_in[4];
  const float* prompt = (const float*)d_in[5];
  const float* gate   = (const float*)d_in[6];
  const float* fcos   = (const float*)d_in[7];
  const float* fsin   = (const float*)d_in[8];
  float* out = (float*)d_out;
  char* ws = (char*)d_ws;

  size_t o = 0;
  bf16* xb  = (bf16*)(ws + o); o += (size_t)8388608 * 2;
  bf16* wqb = (bf16*)(ws + o); o += (size_t)16777216 * 2;
  bf16* wkb = (bf16*)(ws + o); o += (size_t)16777216 * 2;
  bf16* wvb = (bf16*)(ws + o); o += (size_t)16777216 * 2;
  bf16* wob = (bf16*)(ws + o); o += (size_t)16777216 * 2;
  bf16* pb  = (bf16*)(ws + o); o += (size_t)40960 * 2;
  bf16* q_ws  = (bf16*)(ws + o); o += (size_t)2048 * 4096 * 2;
  bf16* k_ws  = (bf16*)(ws + o); o += (size_t)2048 * 4096 * 2;
  bf16* v_ws  = (bf16*)(ws + o); o += (size_t)2048 * 4096 * 2;
  bf16* vT_ws = (bf16*)(ws + o); o += (size_t)2048 * 4096 * 2;
  bf16* pk_ws = (bf16*)(ws + o); o += (size_t)40960 * 2;
  bf16* pv_ws = (bf16*)(ws + o); o += (size_t)40960 * 2;
  bf16* attn_ws = v_ws;

  // 1. downcast inputs to bf16
  cvt6<<<dim3(36884), 256, 0, stream>>>(x, wq, wk, wv, wo, prompt,
                                        xb, wqb, wkb, wvb, wob, pb);
  // 2. QKV (+prompt K/V rows): 9 m-tiles x 16 n-tiles per z (144 % 8 == 0)
  gemm_bt<<<dim3(144, 1, 3), 512, 0, stream>>>(
      xb, pb, wqb, wkb, wvb, q_ws, k_ws, v_ws, pk_ws, pv_ws, (float*)0, 2048, 2058);
  // 3. RoPE on q, k
  rope_qk<<<dim3(2048, 2), 256, 0, stream>>>(q_ws, k_ws, fcos, fsin);
  // 4. V -> VT
  transpose_v<<<dim3(16, 64), 256, 0, stream>>>(v_ws, vT_ws);
  // 5. flash attention + gated prompt attention
  flash_attn<<<dim3(16, 64), 256, 0, stream>>>(
      q_ws, k_ws, vT_ws, pk_ws, pv_ws, gate, attn_ws);
  // 6. output projection (f32 out): 8 x 16 tiles (128 % 8 == 0)
  gemm_bt<<<dim3(128, 1, 1), 512, 0, stream>>>(
      attn_ws, (const bf16*)0, wob, wob, wob, q_ws, q_ws, q_ws,
      (bf16*)0, (bf16*)0, out, 2048, 2048);
}

// Round 5
// 530.467 us; speedup vs baseline: 1.3075x; 1.0272x over previous
//
#include <hip/hip_runtime.h>
#include <hip/hip_bf16.h>
#include <stdint.h>

typedef __hip_bfloat16 bf16;
typedef __attribute__((ext_vector_type(8))) short short8;
typedef __attribute__((ext_vector_type(4))) float f32x4;

#define SCALE_ 0.08838834764831845f  // 1/sqrt(128)

static __device__ __forceinline__ float bf2f(short u) {
  unsigned int x = ((unsigned int)(unsigned short)u) << 16;
  return __builtin_bit_cast(float, x);
}
static __device__ __forceinline__ short f2bf(float f) {
  __hip_bfloat16 h = __float2bfloat16(f);
  return __builtin_bit_cast(short, h);
}
static __device__ __forceinline__ f32x4 mfma16(short8 a, short8 b, f32x4 c) {
  return __builtin_amdgcn_mfma_f32_16x16x32_bf16(a, b, c, 0, 0, 0);
}
static __device__ __forceinline__ void gl_lds16(const bf16* g, bf16* l) {
  __builtin_amdgcn_global_load_lds(
      (const __attribute__((address_space(1))) unsigned int*)g,
      (__attribute__((address_space(3))) unsigned int*)l, 16, 0, 0);
}

// ---------------------------------------------------------------------------
// f32 -> bf16 conversion for x, wq, wk, wv, wo, prompt (one fused launch).
// ---------------------------------------------------------------------------
__global__ __launch_bounds__(256) void cvt6(
    const float* __restrict__ sx, const float* __restrict__ sq,
    const float* __restrict__ sk, const float* __restrict__ sv,
    const float* __restrict__ so, const float* __restrict__ sp,
    bf16* __restrict__ dx, bf16* __restrict__ dq, bf16* __restrict__ dk,
    bf16* __restrict__ dv, bf16* __restrict__ d4, bf16* __restrict__ dp)
{
  int b = blockIdx.x;
  const float* s; bf16* d; int off;
  if (b < 4096)       { s = sx; d = dx; off = b; }
  else if (b < 12288) { s = sq; d = dq; off = b - 4096; }
  else if (b < 20480) { s = sk; d = dk; off = b - 12288; }
  else if (b < 28672) { s = sv; d = dv; off = b - 20480; }
  else if (b < 36864) { s = so; d = d4; off = b - 28672; }
  else                { s = sp; d = dp; off = b - 36864; }
  long base = (long)off * 2048 + threadIdx.x * 8;
  f32x4 a = *(const f32x4*)(s + base);
  f32x4 c = *(const f32x4*)(s + base + 4);
  short8 o;
#pragma unroll
  for (int j = 0; j < 4; j++) { o[j] = f2bf(a[j]); o[4 + j] = f2bf(c[j]); }
  *(short8*)(d + base) = o;
}

// ---------------------------------------------------------------------------
// GEMM: C[m][n] = sum_k A[m][k] * Bw[n][k]  (A: MxK row-major, Bw: NxK row-major)
// 256x256 tile, BK=64, 8 waves (2m x 4n), per-wave 128x64.
// 8-PHASE schedule (T3+T4): K-tile split into 4 stage-units of 16KB
// (A-ks0, B-ks0, A-ks1, B-ks1); per phase: {vmcnt(4); barrier; stage 1 unit
// of kt+1; 4-8 ds_read_b128; lgkmcnt(0); 16 MFMA (setprio-wrapped)}.
// 8 LDS slots (128 KiB) = 2 K-tiles circular; stage order identical across
// waves, so vmcnt(4)+barrier certifies all-but-last-2 units complete; every
// unit is consumed >= 1 phase after its certification (derivation in notes).
// LDS swizzle: 128B line = 2 rows; slot s = (row&1)*4 + (c ^ ((row>>1)&3))
// -> 16 lanes spread over 8 slots = 2-way (free). gl_lds writes linearly;
// inverse permutation applied on the GLOBAL source (rule 21).
// Rows >= M1 come from A2 (prompt, clamped); outputs >= M1 go to Cp.
// CF != null -> f32 output (out-projection).
// ---------------------------------------------------------------------------
__global__ __launch_bounds__(512, 2) void gemm_bt(
    const bf16* __restrict__ A, const bf16* __restrict__ A2,
    const bf16* __restrict__ B0, const bf16* __restrict__ B1, const bf16* __restrict__ B2w,
    bf16* __restrict__ C0, bf16* __restrict__ C1, bf16* __restrict__ C2,
    bf16* __restrict__ P1, bf16* __restrict__ P2,
    float* __restrict__ CF,
    int M1, int Mtot)
{
  __shared__ char lds[131072];   // 8 units x 16KB (2 K-tiles x {A0,B0,A1,B1})
  const int tid = threadIdx.x, w = tid >> 6, l = tid & 63;
  const int lr = l & 15, lg = l >> 4;
  const int wm = w >> 2, wn = w & 3;
  const int z = blockIdx.z;
  const bf16* Bw = (z == 0) ? B0 : ((z == 1) ? B1 : B2w);
  bf16* C  = (z == 0) ? C0 : ((z == 1) ? C1 : C2);
  bf16* Cp = (z == 0) ? (bf16*)0 : ((z == 1) ? P1 : P2);

  // T1: bijective chunked XCD swizzle (gridDim.x % 8 == 0), n fastest.
  const int cpx = gridDim.x >> 3, orig = blockIdx.x;
  const int wg = (orig & 7) * cpx + (orig >> 3);
  const long m0 = (long)(wg >> 4) * 256;
  const long n0 = (long)(wg & 15) * 256;

  // ---- staging source mapping (phys chunk P = tid, tid+512) ----
  // line = P>>3, s = P&7, row = 2*line + (s>>2), c = (s&3)^(line&3)
  const int r0 = ((tid >> 3) << 1) | ((tid >> 2) & 1);
  const int c0 = (tid & 3) ^ ((tid >> 3) & 3);
  const bf16 *pa0, *pa1;
  {
    long mx = (long)(Mtot - M1) - 1;
    long g0 = m0 + r0, g1 = m0 + r0 + 128;
    const bf16 *q0, *q1;
    if (g0 < M1) q0 = A + g0 * 4096;
    else { long rr = g0 - M1; if (rr > mx) rr = mx; q0 = A2 + rr * 4096; }
    if (g1 < M1) q1 = A + g1 * 4096;
    else { long rr = g1 - M1; if (rr > mx) rr = mx; q1 = A2 + rr * 4096; }
    pa0 = q0 + c0 * 8;
    pa1 = q1 + c0 * 8;
  }
  const bf16* pb0 = Bw + (n0 + r0) * 4096 + c0 * 8;
  const bf16* pb1 = pb0 + (long)128 * 4096;

  // ---- fragment-read offsets (swizzled; verified inverse of staging map) ----
  const int ro  = (lr >> 1) * 128 + (((lr & 1) * 4) + (lg ^ ((lr >> 1) & 3))) * 16;
  const int aro = wm * 8192 + ro;   // + mi*1024 within A unit
  const int bro = wn * 4096 + ro;   // + ni*1024 within B unit

  f32x4 acc[8][4];
#pragma unroll
  for (int i = 0; i < 8; i++)
#pragma unroll
    for (int j = 0; j < 4; j++) acc[i][j] = (f32x4){0.f, 0.f, 0.f, 0.f};

  short8 af[4], bf[4];

  // stage unit J_ of a K-tile (k-elem offset KE_) into parity base PSB_
#define STG(PSB_, J_, P0_, P1_, KE_)                                         \
  {                                                                          \
    bf16* d_ = (bf16*)(lds + (PSB_) + (J_) * 16384) + tid * 8;               \
    gl_lds16((P0_) + (KE_), d_);                                             \
    gl_lds16((P1_) + (KE_), d_ + 4096);                                      \
  }

#define PHASE(VMS_, PRB_, AU_, BU_, MO_, LB_, STGC_)                         \
  {                                                                          \
    asm volatile("s_waitcnt vmcnt(" VMS_ ")" ::: "memory");                  \
    __builtin_amdgcn_s_barrier();                                            \
    __builtin_amdgcn_sched_barrier(0);                                       \
    STGC_                                                                    \
    const char* ab_ = lds + (PRB_) + (AU_) + aro;                            \
    _Pragma("unroll") for (int mi = 0; mi < 4; mi++)                         \
      af[mi] = *(const short8*)(ab_ + ((MO_) + mi) * 1024);                  \
    if (LB_) {                                                               \
      const char* bb_ = lds + (PRB_) + (BU_) + bro;                          \
      _Pragma("unroll") for (int ni = 0; ni < 4; ni++)                       \
        bf[ni] = *(const short8*)(bb_ + ni * 1024);                          \
    }                                                                        \
    asm volatile("s_waitcnt lgkmcnt(0)" ::: "memory");                       \
    __builtin_amdgcn_sched_barrier(0);                                       \
    __builtin_amdgcn_s_setprio(1);                                           \
    _Pragma("unroll") for (int mi = 0; mi < 4; mi++)                         \
      _Pragma("unroll") for (int ni = 0; ni < 4; ni++)                       \
        acc[(MO_) + mi][ni] = mfma16(af[mi], bf[ni], acc[(MO_) + mi][ni]);   \
    __builtin_amdgcn_s_setprio(0);                                           \
  }

  // 4 phases of one K-tile: read parity PRB_, stage kt+1 units into PSB_
#define KTILE(PRB_, PSB_, KE_)                                               \
  PHASE("4", PRB_, 0,     16384, 0, 1, STG(PSB_, 0, pa0, pa1, (KE_)))        \
  PHASE("4", PRB_, 0,     16384, 4, 0, STG(PSB_, 1, pb0, pb1, (KE_)))        \
  PHASE("4", PRB_, 32768, 49152, 0, 1, STG(PSB_, 2, pa0, pa1, (KE_) + 32))   \
  PHASE("4", PRB_, 32768, 49152, 4, 0, STG(PSB_, 3, pb0, pb1, (KE_) + 32))

#define KTILE_LAST(PRB_)                                                     \
  PHASE("4", PRB_, 0,     16384, 0, 1, )                                     \
  PHASE("4", PRB_, 0,     16384, 4, 0, )                                     \
  PHASE("0", PRB_, 32768, 49152, 0, 1, )                                     \
  PHASE("0", PRB_, 32768, 49152, 4, 0, )

  // prologue: stage K-tile 0 into parity-0 slots
  STG(0, 0, pa0, pa1, 0)
  STG(0, 1, pb0, pb1, 0)
  STG(0, 2, pa0, pa1, 32)
  STG(0, 3, pb0, pb1, 32)

  // main loop: 64 K-tiles; kt even reads parity0/stages parity1, odd reverse
  for (int kt = 0; kt < 62; kt += 2) {
    const int ke1 = (kt + 1) * 64;
    const int ke2 = (kt + 2) * 64;
    KTILE(0, 65536, ke1)
    KTILE(65536, 0, ke2)
  }
  KTILE(0, 65536, 4032)   // kt=62: stage kt=63
  KTILE_LAST(65536)       // kt=63

#undef KTILE_LAST
#undef KTILE
#undef PHASE
#undef STG

  // epilogue: C/D layout col=lane&15, row=(lane>>4)*4+j
#pragma unroll
  for (int mi = 0; mi < 8; mi++) {
#pragma unroll
    for (int ni = 0; ni < 4; ni++) {
      long col = n0 + wn * 64 + ni * 16 + lr;
      f32x4 v = acc[mi][ni];
#pragma unroll
      for (int j = 0; j < 4; j++) {
        long row = m0 + wm * 128 + mi * 16 + lg * 4 + j;
        if (CF) {
          CF[row * 4096 + col] = v[j];
        } else if (row < M1) {
          *(short*)(C + row * 4096 + col) = f2bf(v[j]);
        } else if (Cp != 0 && row < Mtot) {
          *(short*)(Cp + (row - M1) * 4096 + col) = f2bf(v[j]);
        }
      }
    }
  }
}

// ---------------------------------------------------------------------------
// RoPE in-place on q / k  ([2048][4096]), freqs f32.
// ---------------------------------------------------------------------------
__global__ __launch_bounds__(256) void rope_qk(
    bf16* __restrict__ Q, bf16* __restrict__ Kb,
    const float* __restrict__ FC, const float* __restrict__ FS)
{
  const int row = blockIdx.x;
  const int s = row & 1023;
  const int t = threadIdx.x;
  bf16* base = (blockIdx.y ? Kb : Q) + (long)row * 4096 + t * 16;
  short8 v0 = *(const short8*)base;
  short8 v1 = *(const short8*)(base + 8);
  const float* cp = FC + s * 64 + (t & 7) * 8;
  const float* sp = FS + s * 64 + (t & 7) * 8;
  f32x4 c0 = *(const f32x4*)cp;
  f32x4 c1 = *(const f32x4*)(cp + 4);
  f32x4 s0 = *(const f32x4*)sp;
  f32x4 s1 = *(const f32x4*)(sp + 4);
  short8 o0, o1;
#pragma unroll
  for (int j = 0; j < 4; j++) {
    float c = c0[j], sn = s0[j];
    float e = bf2f(v0[2 * j]), od = bf2f(v0[2 * j + 1]);
    o0[2 * j] = f2bf(e * c - od * sn);
    o0[2 * j + 1] = f2bf(e * sn + od * c);
    float c2 = c1[j], sn2 = s1[j];
    float e2 = bf2f(v1[2 * j]), od2 = bf2f(v1[2 * j + 1]);
    o1[2 * j] = f2bf(e2 * c2 - od2 * sn2);
    o1[2 * j + 1] = f2bf(e2 * sn2 + od2 * c2);
  }
  *(short8*)base = o0;
  *(short8*)(base + 8) = o1;
}

// ---------------------------------------------------------------------------
// V transpose: v[b][s][h][d] -> vT[bh][d][s]
// ---------------------------------------------------------------------------
__global__ __launch_bounds__(256) void transpose_v(
    const bf16* __restrict__ V, bf16* __restrict__ VT)
{
  __shared__ bf16 T[64 * 128];
  const int tid = threadIdx.x;
  const int st = blockIdx.x * 64, bh = blockIdx.y;
  const int b = bh >> 5, h = bh & 31;
  const bf16* src = V + ((long)(b * 1024 + st)) * 4096 + h * 128;
#pragma unroll
  for (int rr = 0; rr < 4; ++rr) {
    int i = tid + rr * 256;
    int s_l = i >> 4, c = i & 15;
    short8 v = *(const short8*)(src + (long)s_l * 4096 + c * 8);
    *(short8*)((char*)T + s_l * 256 + ((c ^ (s_l & 7)) * 16)) = v;
  }
  __syncthreads();
#pragma unroll
  for (int rr = 0; rr < 4; ++rr) {
    int i = tid + rr * 256;
    int d = i >> 3, cs = i & 7;
    short8 ov;
#pragma unroll
    for (int e = 0; e < 8; e++) {
      int s_l = cs * 8 + e;
      ov[e] = *(const short*)((char*)T + s_l * 256 + (((d >> 3) ^ (s_l & 7)) * 16) + (d & 7) * 2);
    }
    *(short8*)(VT + ((long)bh * 128 + d) * 1024 + st + cs * 8) = ov;
  }
}

// ---------------------------------------------------------------------------
// Flash attention, causal, + fused gated prompt attention. (unchanged, passing)
// ---------------------------------------------------------------------------
__global__ __launch_bounds__(256) void flash_attn(
    const bf16* __restrict__ Q, const bf16* __restrict__ Kg, const bf16* __restrict__ VT,
    const bf16* __restrict__ PK, const bf16* __restrict__ PV,
    const float* __restrict__ GATE, bf16* __restrict__ O)
{
  __shared__ bf16 Kl[32 * 128];
  __shared__ bf16 Vl[128 * 32];
  __shared__ bf16 PKl[16 * 128];
  __shared__ bf16 PVl[128 * 16];
  __shared__ bf16 Pl[4][16 * 32];
  const int tid = threadIdx.x, w = tid >> 6, l = tid & 63;
  const int lg = l >> 4, lr = l & 15;
  const int qb = blockIdx.x, bh = blockIdx.y;
  const int b = bh >> 5, h = bh & 31;
  const int q0 = qb * 64 + w * 16;

  short8 qf[4];
  {
    const bf16* qp = Q + ((long)(b * 1024 + q0 + lr)) * 4096 + h * 128 + lg * 8;
#pragma unroll
    for (int c = 0; c < 4; c++) qf[c] = *(const short8*)(qp + c * 32);
  }
  {
    int rowp = tid >> 4, pc = tid & 15, lc = pc ^ (rowp & 7);
    short8 v = {0, 0, 0, 0, 0, 0, 0, 0};
    if (rowp < 10) v = *(const short8*)(PK + (long)rowp * 4096 + h * 128 + lc * 8);
    *(short8*)((char*)PKl + tid * 16) = v;
  }
  {
    int d = tid >> 1, pb = (tid & 1) * 8;
#pragma unroll
    for (int e = 0; e < 8; e++) {
      int p = pb + e;
      short v = 0;
      if (p < 10) v = __builtin_bit_cast(short, PV[(long)p * 4096 + h * 128 + d]);
      *(short*)((char*)PVl + d * 32 + (((p >> 3) ^ (d & 1)) * 16) + (p & 7) * 2) = v;
    }
  }
  const float gate = GATE[h];

  f32x4 o[8];
#pragma unroll
  for (int i = 0; i < 8; i++) o[i] = (f32x4){0.f, 0.f, 0.f, 0.f};
  float m_[4] = {-1e30f, -1e30f, -1e30f, -1e30f};
  float l_[4] = {0.f, 0.f, 0.f, 0.f};

  const int nt = (qb + 1) * 2;
  const bf16* Kbase = Kg + ((long)b * 1024) * 4096 + h * 128;
  const bf16* Vbase = VT + ((long)bh) * 128 * 1024;
  const int cb1 = w * 64, cb2 = 256 + w * 64;
  const int iA = cb1 + l, iB = cb2 + l;
  bf16* pw = &Pl[w][0];

  for (int j = 0; j < nt; ++j) {
    __syncthreads();
    {
      const bf16* gA = Kbase + (long)(j * 32 + (iA >> 4)) * 4096 + ((iA & 15) ^ ((iA >> 4) & 7)) * 8;
      const bf16* gB = Kbase + (long)(j * 32 + (iB >> 4)) * 4096 + ((iB & 15) ^ ((iB >> 4) & 7)) * 8;
      gl_lds16(gA, Kl + cb1 * 8);
      gl_lds16(gB, Kl + cb2 * 8);
      const bf16* vA = Vbase + (long)(iA >> 2) * 1024 + j * 32 + ((iA & 3) ^ ((iA >> 2) & 3)) * 8;
      const bf16* vB = Vbase + (long)(iB >> 2) * 1024 + j * 32 + ((iB & 3) ^ ((iB >> 2) & 3)) * 8;
      gl_lds16(vA, Vl + cb1 * 8);
      gl_lds16(vB, Vl + cb2 * 8);
    }
    __syncthreads();

    f32x4 s[2];
#pragma unroll
    for (int ns = 0; ns < 2; ns++) {
      f32x4 a = (f32x4){0.f, 0.f, 0.f, 0.f};
      int krow = ns * 16 + lr;
      const char* kp = (const char*)Kl + krow * 256;
      int sw = krow & 7;
#pragma unroll
      for (int c = 0; c < 4; c++) {
        short8 kf = *(const short8*)(kp + (((c * 4 + lg) ^ sw) * 16));
        a = mfma16(qf[c], kf, a);
      }
      int key = j * 32 + krow;
#pragma unroll
      for (int r = 0; r < 4; r++) {
        int qr = q0 + lg * 4 + r;
        s[ns][r] = a[r] * SCALE_ + ((key <= qr) ? 0.0f : -1e30f);
      }
    }
    float mx[4], cor[4], sum[4];
#pragma unroll
    for (int r = 0; r < 4; r++) mx[r] = fmaxf(s[0][r], s[1][r]);
#pragma unroll
    for (int xm = 1; xm < 16; xm <<= 1)
#pragma unroll
      for (int r = 0; r < 4; r++) mx[r] = fmaxf(mx[r], __shfl_xor(mx[r], xm, 64));
#pragma unroll
    for (int r = 0; r < 4; r++) {
      float mn = fmaxf(m_[r], mx[r]);
      cor[r] = __expf(m_[r] - mn);
      m_[r] = mn;
      s[0][r] = __expf(s[0][r] - mn);
      s[1][r] = __expf(s[1][r] - mn);
      sum[r] = s[0][r] + s[1][r];
    }
#pragma unroll
    for (int xm = 1; xm < 16; xm <<= 1)
#pragma unroll
      for (int r = 0; r < 4; r++) sum[r] += __shfl_xor(sum[r], xm, 64);
#pragma unroll
    for (int r = 0; r < 4; r++) l_[r] = l_[r] * cor[r] + sum[r];
#pragma unroll
    for (int df = 0; df < 8; df++)
#pragma unroll
      for (int r = 0; r < 4; r++) o[df][r] *= cor[r];

#pragma unroll
    for (int ns = 0; ns < 2; ns++)
#pragma unroll
      for (int r = 0; r < 4; r++)
        *(short*)((char*)pw + ((lg * 4 + r) * 32 + ns * 16 + lr) * 2) = f2bf(s[ns][r]);
    asm volatile("s_waitcnt lgkmcnt(0)" ::: "memory");
    __builtin_amdgcn_sched_barrier(0);
    short8 pf = *(const short8*)(pw + lr * 32 + lg * 8);

#pragma unroll
    for (int df = 0; df < 8; df++) {
      int d = df * 16 + lr;
      short8 vf = *(const short8*)((const char*)Vl + d * 64 + ((lg ^ (d & 3)) * 16));
      o[df] = mfma16(pf, vf, o[df]);
    }
  }

  // ---- prompt attention ----
  f32x4 ps;
  {
    f32x4 a = (f32x4){0.f, 0.f, 0.f, 0.f};
    const char* kp = (const char*)PKl + lr * 256;
    int sw = lr & 7;
#pragma unroll
    for (int c = 0; c < 4; c++) {
      short8 kf = *(const short8*)(kp + (((c * 4 + lg) ^ sw) * 16));
      a = mfma16(qf[c], kf, a);
    }
#pragma unroll
    for (int r = 0; r < 4; r++) ps[r] = (lr < 10) ? a[r] * SCALE_ : -1e30f;
  }
  {
    float pm[4], pss[4];
#pragma unroll
    for (int r = 0; r < 4; r++) pm[r] = ps[r];
#pragma unroll
    for (int xm = 1; xm < 16; xm <<= 1)
#pragma unroll
      for (int r = 0; r < 4; r++) pm[r] = fmaxf(pm[r], __shfl_xor(pm[r], xm, 64));
#pragma unroll
    for (int r = 0; r < 4; r++) { ps[r] = __expf(ps[r] - pm[r]); pss[r] = ps[r]; }
#pragma unroll
    for (int xm = 1; xm < 16; xm <<= 1)
#pragma unroll
      for (int r = 0; r < 4; r++) pss[r] += __shfl_xor(pss[r], xm, 64);
#pragma unroll
    for (int r = 0; r < 4; r++) ps[r] = ps[r] / pss[r];
  }
#pragma unroll
  for (int r = 0; r < 4; r++) {
    *(short*)((char*)pw + ((lg * 4 + r) * 32 + lr) * 2) = f2bf(ps[r]);
    *(short*)((char*)pw + ((lg * 4 + r) * 32 + 16 + lr) * 2) = 0;
  }
  asm volatile("s_waitcnt lgkmcnt(0)" ::: "memory");
  __builtin_amdgcn_sched_barrier(0);
  short8 pf2 = *(const short8*)(pw + lr * 32 + lg * 8);
  f32x4 po[8];
#pragma unroll
  for (int df = 0; df < 8; df++) {
    int d = df * 16 + lr;
    short8 vf = {0, 0, 0, 0, 0, 0, 0, 0};
    if (lg < 2) vf = *(const short8*)((const char*)PVl + d * 32 + ((lg ^ (d & 1)) * 16));
    po[df] = mfma16(pf2, vf, (f32x4){0.f, 0.f, 0.f, 0.f});
  }

  bf16* op = O + ((long)(b * 1024 + q0 + lg * 4)) * 4096 + h * 128 + lr;
#pragma unroll
  for (int df = 0; df < 8; df++)
#pragma unroll
    for (int r = 0; r < 4; r++) {
      float val = o[df][r] / l_[r] + gate * po[df][r];
      *(short*)(op + (long)r * 4096 + df * 16) = f2bf(val);
    }
}

// ---------------------------------------------------------------------------
extern "C" void kernel_launch(void* const* d_in, const int* in_sizes, int n_in,
                              void* d_out, int out_size, void* d_ws, size_t ws_size,
                              hipStream_t stream) {
  (void)in_sizes; (void)n_in; (void)out_size; (void)ws_size;
  const float* x      = (const float*)d_in[0];
  const float* wq     = (const float*)d_in[1];
  const float* wk     = (const float*)d_in[2];
  const float* wv     = (const float*)d_in[3];
  const float* wo     = (const float*)d_in[4];
  const float* prompt = (const float*)d_in[5];
  const float* gate   = (const float*)d_in[6];
  const float* fcos   = (const float*)d_in[7];
  const float* fsin   = (const float*)d_in[8];
  float* out = (float*)d_out;
  char* ws = (char*)d_ws;

  size_t o = 0;
  bf16* xb  = (bf16*)(ws + o); o += (size_t)8388608 * 2;
  bf16* wqb = (bf16*)(ws + o); o += (size_t)16777216 * 2;
  bf16* wkb = (bf16*)(ws + o); o += (size_t)16777216 * 2;
  bf16* wvb = (bf16*)(ws + o); o += (size_t)16777216 * 2;
  bf16* wob = (bf16*)(ws + o); o += (size_t)16777216 * 2;
  bf16* pb  = (bf16*)(ws + o); o += (size_t)40960 * 2;
  bf16* q_ws  = (bf16*)(ws + o); o += (size_t)2048 * 4096 * 2;
  bf16* k_ws  = (bf16*)(ws + o); o += (size_t)2048 * 4096 * 2;
  bf16* v_ws  = (bf16*)(ws + o); o += (size_t)2048 * 4096 * 2;
  bf16* vT_ws = (bf16*)(ws + o); o += (size_t)2048 * 4096 * 2;
  bf16* pk_ws = (bf16*)(ws + o); o += (size_t)40960 * 2;
  bf16* pv_ws = (bf16*)(ws + o); o += (size_t)40960 * 2;
  bf16* attn_ws = v_ws;

  // 1. downcast inputs to bf16
  cvt6<<<dim3(36884), 256, 0, stream>>>(x, wq, wk, wv, wo, prompt,
                                        xb, wqb, wkb, wvb, wob, pb);
  // 2. QKV (+prompt K/V rows): 9 m-tiles x 16 n-tiles per z (144 % 8 == 0)
  gemm_bt<<<dim3(144, 1, 3), 512, 0, stream>>>(
      xb, pb, wqb, wkb, wvb, q_ws, k_ws, v_ws, pk_ws, pv_ws, (float*)0, 2048, 2058);
  // 3. RoPE on q, k
  rope_qk<<<dim3(2048, 2), 256, 0, stream>>>(q_ws, k_ws, fcos, fsin);
  // 4. V -> VT
  transpose_v<<<dim3(16, 64), 256, 0, stream>>>(v_ws, vT_ws);
  // 5. flash attention + gated prompt attention
  flash_attn<<<dim3(16, 64), 256, 0, stream>>>(
      q_ws, k_ws, vT_ws, pk_ws, pv_ws, gate, attn_ws);
  // 6. output projection (f32 out): 8 x 16 tiles (128 % 8 == 0)
  gemm_bt<<<dim3(128, 1, 1), 512, 0, stream>>>(
      attn_ws, (const bf16*)0, wob, wob, wob, q_ws, q_ws, q_ws,
      (bf16*)0, (bf16*)0, out, 2048, 2048);
}